// Round 11
// baseline (341.717 us; speedup 1.0000x reference)
//
#include <hip/hip_runtime.h>
#include <hip/hip_bf16.h>

typedef __hip_bfloat16 bf16;
typedef __attribute__((ext_vector_type(8))) short short8;
typedef __attribute__((ext_vector_type(4))) float f32x4;

#define F_BIAS 1
#define F_RELU 2
#define F_RES  4

__device__ __forceinline__ void st_out(float* p, float v){ *p = v; }
__device__ __forceinline__ void st_out(bf16* p, float v){ *p = __float2bfloat16(v); }
__device__ __forceinline__ short f2bs(float f){
  bf16 h = __float2bfloat16(f);
  return *reinterpret_cast<short*>(&h);
}

// async global->LDS, 16 B per lane (linear LDS dest, pre-swizzled global src).
__device__ __forceinline__ void gl_lds16(const void* g, void* l){
  __builtin_amdgcn_global_load_lds(
      (const __attribute__((address_space(1))) void*)g,
      (__attribute__((address_space(3))) void*)l, 16, 0, 0);
}

// LDS-only barrier: orders ds ops, leaves global_load_lds (vmcnt) in flight.
__device__ __forceinline__ void lgkm_barrier(){
  asm volatile("s_waitcnt lgkmcnt(0)" ::: "memory");
  __builtin_amdgcn_s_barrier();
}

// ---------------- prologue: weight prep + LN(x_T) + LN(x_S) ----------------
struct ProArgs {
  const float* wsrc[10];
  bf16* wdst[10];
  const float *xT, *xS, *tl1w, *tl1b, *sl1w, *sl1b;
  bf16 *hT, *hS;
};

template<int RL>
__device__ __forceinline__ void wave_ln(bf16* __restrict__ dst,
    const float* __restrict__ src, const float* __restrict__ w,
    const float* __restrict__ bvec, int row){
  int lane = threadIdx.x & 63;
  const float* s = src + (size_t)row*RL;
  float4 v0 = *(const float4*)(s + lane*4);
  float4 v1 = {0.f,0.f,0.f,0.f};
  float sum = v0.x+v0.y+v0.z+v0.w;
  float sq  = v0.x*v0.x+v0.y*v0.y+v0.z*v0.z+v0.w*v0.w;
  if (RL == 512){
    v1 = *(const float4*)(s + 256 + lane*4);
    sum += v1.x+v1.y+v1.z+v1.w;
    sq  += v1.x*v1.x+v1.y*v1.y+v1.z*v1.z+v1.w*v1.w;
  }
  #pragma unroll
  for (int off=32; off; off>>=1){
    sum += __shfl_xor(sum, off, 64);
    sq  += __shfl_xor(sq , off, 64);
  }
  const float inv = 1.0f/(float)RL;
  float mean = sum*inv;
  float rstd = rsqrtf(sq*inv - mean*mean + 1e-6f);
  float4 w0 = *(const float4*)(w + lane*4);
  float4 b0 = *(const float4*)(bvec + lane*4);
  bf16* d = dst + (size_t)row*RL;
  short4 o;
  o.x = f2bs((v0.x-mean)*rstd*w0.x + b0.x);
  o.y = f2bs((v0.y-mean)*rstd*w0.y + b0.y);
  o.z = f2bs((v0.z-mean)*rstd*w0.z + b0.z);
  o.w = f2bs((v0.w-mean)*rstd*w0.w + b0.w);
  *(short4*)((short*)d + lane*4) = o;
  if (RL == 512){
    float4 w1 = *(const float4*)(w + 256 + lane*4);
    float4 b1 = *(const float4*)(bvec + 256 + lane*4);
    short4 o1;
    o1.x = f2bs((v1.x-mean)*rstd*w1.x + b1.x);
    o1.y = f2bs((v1.y-mean)*rstd*w1.y + b1.y);
    o1.z = f2bs((v1.z-mean)*rstd*w1.z + b1.z);
    o1.w = f2bs((v1.w-mean)*rstd*w1.w + b1.w);
    *(short4*)((short*)d + 256 + lane*4) = o1;
  }
}

__global__ __launch_bounds__(256) void prologue(ProArgs a){
  int blk = blockIdx.x;
  int wid = threadIdx.x >> 6;
  if (blk < 1792){
    int v = blk*256 + threadIdx.x;
    int e = v*4;
    int seg = (e>=65536)+(e>=131072)+(e>=196608)+(e>=262144)+(e>=524288)
            + (e>=786432)+(e>=1048576)+(e>=1310720)+(e>=1572864);
    const int starts[10] = {0,65536,131072,196608,262144,524288,786432,
                            1048576,1310720,1572864};
    int off = e - starts[seg];
    float4 f = *(const float4*)(a.wsrc[seg] + off);
    short4 o;
    o.x = f2bs(f.x); o.y = f2bs(f.y); o.z = f2bs(f.z); o.w = f2bs(f.w);
    *(short4*)((short*)a.wdst[seg] + off) = o;
  } else if (blk < 1792 + 2048){
    wave_ln<256>(a.hT, a.xT, a.tl1w, a.tl1b, (blk-1792)*4 + wid);
  } else {
    wave_ln<512>(a.hS, a.xS, a.sl1w, a.sl1b, (blk-3840)*4 + wid);
  }
}

// -- MFMA bf16 GEMM body (256 thr): dbuf, barrier at TOP ---------------------
template<int BM, int BN, int BK>
__device__ __forceinline__ void gemm_body(
    short* __restrict__ AsB, short* __restrict__ BsB,
    const bf16* __restrict__ A, const bf16* __restrict__ B,
    float* __restrict__ outF, bf16* __restrict__ outB,
    const float* __restrict__ bias, const float* __restrict__ resid,
    int K, int lda, int ldb, int ldc, int flags, int m0, int n0){
  int tid = threadIdx.x;
  int w = tid>>6, lane = tid&63, quad = lane>>4, l16 = lane&15;
  constexpr int MF  = BM/32;
  constexpr int NF  = BN/32;
  constexpr int CPR = BK/8;
  constexpr int CA  = BM*CPR/256;
  constexpr int CB  = BN*CPR/256;
  int wm = (w>>1)*(BM/2), wn = (w&1)*(BN/2);
  f32x4 acc[MF][NF];
  #pragma unroll
  for (int r=0;r<MF;r++)
    #pragma unroll
    for (int j=0;j<NF;j++)
      acc[r][j] = (f32x4){0.f,0.f,0.f,0.f};

  auto stage = [&](int k0, int half){
    short* as = AsB + half*(BM*BK);
    short* bs = BsB + half*(BN*BK);
    #pragma unroll
    for (int c=0;c<CA;c++){
      int ch = tid + c*256;
      int row = ch / CPR, p = ch % CPR;
      gl_lds16(A + (size_t)(m0+row)*lda + k0 + ((p ^ (row&(CPR-1)))*8),
               &as[row*BK + p*8]);
    }
    #pragma unroll
    for (int c=0;c<CB;c++){
      int ch = tid + c*256;
      int row = ch / CPR, p = ch % CPR;
      gl_lds16(B + (size_t)(n0+row)*ldb + k0 + ((p ^ (row&(CPR-1)))*8),
               &bs[row*BK + p*8]);
    }
  };

  stage(0, 0);
  int nk = K / BK;
  for (int t = 0; t < nk; ++t){
    __syncthreads();
    if (t+1 < nk) stage((t+1)*BK, (t+1)&1);
    const short* as = AsB + (t&1)*(BM*BK);
    const short* bs = BsB + (t&1)*(BN*BK);
    #pragma unroll
    for (int ks=0; ks<BK/32; ++ks){
      short8 af[MF], bfr[NF];
      #pragma unroll
      for (int r=0;r<MF;r++){
        int rr = wm + r*16 + l16;
        af[r] = *(short8*)&as[rr*BK + (((ks*4+quad) ^ (rr&(CPR-1)))*8)];
      }
      #pragma unroll
      for (int j=0;j<NF;j++){
        int rr = wn + j*16 + l16;
        bfr[j] = *(short8*)&bs[rr*BK + (((ks*4+quad) ^ (rr&(CPR-1)))*8)];
      }
      #pragma unroll
      for (int r=0;r<MF;r++)
        #pragma unroll
        for (int j=0;j<NF;j++)
          acc[r][j] = __builtin_amdgcn_mfma_f32_16x16x32_bf16(af[r], bfr[j], acc[r][j], 0,0,0);
    }
  }
  #pragma unroll
  for (int r=0;r<MF;r++){
    int mb = m0 + wm + r*16 + quad*4;
    #pragma unroll
    for (int j=0;j<NF;j++){
      int n = n0 + wn + j*16 + l16;
      float bv = (flags & F_BIAS) ? bias[n] : 0.0f;
      #pragma unroll
      for (int e=0;e<4;e++){
        float v = acc[r][j][e] + bv;
        if (flags & F_RELU) v = fmaxf(v, 0.0f);
        long long idx = (long long)(mb+e)*ldc + n;
        if (flags & F_RES) v += resid[idx];
        if (outF) outF[idx] = v;
        if (outB) st_out(outB + idx, v);
      }
    }
  }
}

// ---- dual GEMM: two independent <128,128> GEMMs in one launch (1-D grid) ---
struct GArgs {
  const bf16 *A, *B;
  float* outF; bf16* outB;
  const float *bias, *resid;
  int K, lda, ldb, ldc, flags, ty;
};
__global__ __launch_bounds__(256) void gemm_dual(GArgs g0, GArgs g1, int n0){
  __shared__ __align__(16) short As[2*128*64];
  __shared__ __align__(16) short Bs[2*128*64];
  int id = blockIdx.x;
  bool first = id < n0;
  const GArgs& g = first ? g0 : g1;
  int t = first ? id : id - n0;
  int bx = t / g.ty, by = t - bx*g.ty;
  gemm_body<128,128,64>(As, Bs, g.A, g.B, g.outF, g.outB, g.bias, g.resid,
                        g.K, g.lda, g.ldb, g.ldc, g.flags, bx*128, by*128);
}

// ---- lnffn v3: 1024 threads (16 waves/CU), weights direct from global -----
// x = A@Bm^T + resid ; h = LN(x) ; out = relu(h@W1^T+b1)@W2^T + b2 + x
// x register-carried; Hin/Hs LDS-only (80 KB). Grid stays 256 (weight L2
// traffic unchanged); 16 waves/block = 4 waves/SIMD for latency hiding.
struct LnFfnArgs {
  const bf16 *A;        // [*,256] bf16 GEMM A
  const bf16 *Bm;       // [256,256] bf16 GEMM B (Wo or sw[b])
  const float *resid0;  // f32 resid for x
  const float *lnw, *lnb;
  const bf16 *W1; const float *B1;   // [1024,256], [1024]
  const bf16 *W2; const float *B2;   // [256,1024], [256]
  float *outF; bf16 *outB;
  long long sA, sB, sR, sO;          // per-blockIdx.z element strides
};

__global__ __launch_bounds__(1024) void lnffn(LnFfnArgs a){
  __shared__ __align__(16) short Hin[32*256];    // 16 KB (XOR g^row)
  __shared__ __align__(16) short Hs[32*1024];    // 64 KB (XOR g^(row&7))
  // LN reduction scratch overlays the (not-yet-written) head of Hs.
  float (*redS)[32] = (float(*)[32])Hs;          // [8][32] = 1 KB
  float (*redQ)[32] = (float(*)[32])(Hs + 512);  // [8][32] = 1 KB
  int bz = blockIdx.z;
  const bf16* A  = a.A  + (size_t)bz*a.sA;
  const bf16* Bm = a.Bm + (size_t)bz*a.sB;
  long long rbase = (long long)bz*a.sR;
  long long obase = (long long)bz*a.sO;
  int tid = threadIdx.x;
  int w = tid>>6, lane = tid&63, quad = lane>>4, l16 = lane&15;
  int m0 = blockIdx.x*32;
  int wm = (w>>3)*16;         // 0/16 : row half
  int wc = (w&7);             // 0..7 : col octant

  // ------ phase 0: x = A@Bm^T (K=256); wave = 16 rows x 32 cols ------------
  f32x4 acc0[2];
  acc0[0] = (f32x4){0.f,0.f,0.f,0.f};
  acc0[1] = (f32x4){0.f,0.f,0.f,0.f};
  #pragma unroll
  for (int ks=0; ks<8; ++ks){
    short8 af = *(const short8*)(A + (size_t)(m0 + wm + l16)*256 + ks*32 + quad*8);
    #pragma unroll
    for (int j=0;j<2;j++){
      short8 bk = *(const short8*)(Bm + (size_t)(wc*32 + j*16 + l16)*256 + ks*32 + quad*8);
      acc0[j] = __builtin_amdgcn_mfma_f32_16x16x32_bf16(af, bk, acc0[j], 0,0,0);
    }
  }
  // resid add + per-row LN partial sums (this wave covers 32 cols of the row)
  #pragma unroll
  for (int e=0;e<4;e++){
    int row = wm + quad*4 + e;
    float s = 0.f, q2 = 0.f;
    #pragma unroll
    for (int j=0;j<2;j++){
      float v = acc0[j][e] +
                a.resid0[rbase + (long long)(m0+row)*256 + wc*32 + j*16 + l16];
      acc0[j][e] = v;                  // x stays in registers
      s += v; q2 += v*v;
    }
    #pragma unroll
    for (int off=1; off<16; off<<=1){
      s  += __shfl_xor(s , off, 16);
      q2 += __shfl_xor(q2, off, 16);
    }
    if (l16==0){ redS[wc][row] = s; redQ[wc][row] = q2; }
  }
  __syncthreads();
  #pragma unroll
  for (int e=0;e<4;e++){
    int row = wm + quad*4 + e;
    float tot = 0.f, tq = 0.f;
    #pragma unroll
    for (int ww=0; ww<8; ww++){ tot += redS[ww][row]; tq += redQ[ww][row]; }
    float mean = tot * (1.0f/256.0f);
    float var  = tq * (1.0f/256.0f) - mean*mean;
    float rstd = rsqrtf(var + 1e-6f);
    #pragma unroll
    for (int j=0;j<2;j++){
      int col = wc*32 + j*16 + l16;
      float h = (acc0[j][e]-mean)*rstd*a.lnw[col] + a.lnb[col];
      int g = col >> 3;
      Hin[row*256 + ((g ^ row)*8) + (col&7)] = f2bs(h);
    }
  }
  __syncthreads();                     // Hin visible; redS region now dead

  // ------ phase A: H = relu(h@W1^T + b1) -> Hs; W1 direct global -----------
  // wave = 16 rows x 128 hidden cols (2 chunks of 64)
  for (int hc=0; hc<2; ++hc){
    f32x4 acc1[4];
    #pragma unroll
    for (int j=0;j<4;j++) acc1[j] = (f32x4){0.f,0.f,0.f,0.f};
    #pragma unroll
    for (int ks=0; ks<8; ++ks){
      int rr = wm + l16;
      int kk = ks*4 + quad;
      short8 af = *(short8*)&Hin[rr*256 + ((kk ^ rr)*8)];
      #pragma unroll
      for (int j=0;j<4;j++){
        int hr = wc*128 + hc*64 + j*16 + l16;
        short8 bk = *(const short8*)(a.W1 + (size_t)hr*256 + ks*32 + quad*8);
        acc1[j] = __builtin_amdgcn_mfma_f32_16x16x32_bf16(af, bk, acc1[j], 0,0,0);
      }
    }
    #pragma unroll
    for (int j=0;j<4;j++)
      #pragma unroll
      for (int e=0;e<4;e++){
        int row = wm + quad*4 + e;
        int col = wc*128 + hc*64 + j*16 + l16;
        float v = fmaxf(acc1[j][e] + a.B1[col], 0.0f);
        int g = col>>3;
        Hs[row*1024 + ((g ^ (row&7))*8) + (col&7)] = f2bs(v);
      }
  }
  __syncthreads();                     // Hs visible to all waves

  // ------ phase B: out = H@W2^T + b2 + x; W2 direct global -----------------
  f32x4 accB[2];
  accB[0] = (f32x4){0.f,0.f,0.f,0.f};
  accB[1] = (f32x4){0.f,0.f,0.f,0.f};
  #pragma unroll 8
  for (int ks=0; ks<32; ++ks){
    int rr = wm + l16;
    int kk = ks*4 + quad;
    short8 af = *(short8*)&Hs[rr*1024 + ((kk ^ (rr&7))*8)];
    #pragma unroll
    for (int j=0;j<2;j++){
      int n = wc*32 + j*16 + l16;
      short8 bk = *(const short8*)(a.W2 + (size_t)n*1024 + ks*32 + quad*8);
      accB[j] = __builtin_amdgcn_mfma_f32_16x16x32_bf16(af, bk, accB[j], 0,0,0);
    }
  }
  #pragma unroll
  for (int j=0;j<2;j++){
    int n = wc*32 + j*16 + l16;
    float bv = a.B2[n];
    #pragma unroll
    for (int e=0;e<4;e++){
      int row = wm + quad*4 + e;
      long long idx = obase + (long long)(m0+row)*256 + n;
      float v = accB[j][e] + bv + acc0[j][e];   // register-carried x
      a.outF[idx] = v;
      if (a.outB) st_out(a.outB + idx, v);
    }
  }
}

// ---------------- MFMA flash temporal causal attention ----------------
__device__ __forceinline__ int fsw(int row){ return (row>>1)&3; }
__global__ __launch_bounds__(256) void flash_mfma(
    const bf16* __restrict__ qkv, bf16* __restrict__ o){
  int qt = (int)gridDim.x - 1 - (int)blockIdx.x;   // longest blocks first
  int h = blockIdx.y, b = blockIdx.z;
  int tid = threadIdx.x;
  int w = tid>>6, lane = tid&63, quad = lane>>4, l16 = lane&15;
  __shared__ __align__(16) bf16 Qs[64*32];
  __shared__ __align__(16) bf16 Ks[2][64*32];
  __shared__ __align__(16) bf16 Vt[2][32*72];
  __shared__ __align__(16) bf16 Ps[64*72];
  const bf16* base = qkv + (size_t)b*512*768;
  int t0 = qt*64;
  int srow = tid>>2, spos = tid&3;
  gl_lds16(base + (size_t)(t0+srow)*768 + h*32 + ((spos ^ fsw(srow))*8),
           &Qs[srow*32 + spos*8]);
  {
    const bf16* rp = base + (size_t)srow*768 + h*32;
    gl_lds16(rp + 256 + ((spos ^ fsw(srow))*8), &Ks[0][srow*32 + spos*8]);
    short8 v = *(const short8*)(rp + 512 + spos*8);
    #pragma unroll
    for (int q=0;q<8;q++){
      short tmp = v[q];
      Vt[0][(spos*8+q)*72 + srow] = *(bf16*)&tmp;
    }
  }
  f32x4 accO[2];
  accO[0] = (f32x4){0.f,0.f,0.f,0.f};
  accO[1] = (f32x4){0.f,0.f,0.f,0.f};
  float m_i[4], l_i[4];
  #pragma unroll
  for (int e=0;e<4;e++){ m_i[e] = -3.0e38f; l_i[e] = 0.0f; }
  const float scale = 0.17677669529663687f;
  __syncthreads();
  int rq = w*16 + l16;
  short8 aq = *(short8*)&Qs[rq*32 + ((quad ^ fsw(rq))*8)];

  for (int kt = 0; kt <= qt; ++kt){
    if (kt) __syncthreads();
    int cur = kt&1, nxt = cur^1;
    bool pre = (kt < qt);
    short8 vpre;
    if (pre){
      const bf16* rp = base + (size_t)((kt+1)*64 + srow)*768 + h*32;
      gl_lds16(rp + 256 + ((spos ^ fsw(srow))*8), &Ks[nxt][srow*32 + spos*8]);
      vpre = *(const short8*)(rp + 512 + spos*8);
    }
    f32x4 S[4];
    #pragma unroll
    for (int j2=0;j2<4;j2++){
      int rk = j2*16 + l16;
      short8 bk = *(short8*)&Ks[cur][rk*32 + ((quad ^ fsw(rk))*8)];
      S[j2] = __builtin_amdgcn_mfma_f32_16x16x32_bf16(aq, bk,
                (f32x4){0.f,0.f,0.f,0.f}, 0,0,0);
    }
    bool diag = (kt == qt);
    int s0 = kt*64;
    int qrow_base = t0 + w*16 + quad*4;
    #pragma unroll
    for (int e=0;e<4;e++){
      float sv[4];
      #pragma unroll
      for (int j2=0;j2<4;j2++){
        float x = S[j2][e]*scale;
        if (diag && (s0 + j2*16 + l16 > qrow_base + e)) x = -3.0e38f;
        sv[j2] = x;
      }
      float mx = fmaxf(fmaxf(sv[0],sv[1]), fmaxf(sv[2],sv[3]));
      #pragma unroll
      for (int off=1; off<16; off<<=1) mx = fmaxf(mx, __shfl_xor(mx, off, 64));
      float m_new = fmaxf(m_i[e], mx);
      float alpha = __expf(m_i[e]-m_new);
      float rs = 0.0f;
      #pragma unroll
      for (int j2=0;j2<4;j2++){
        float p = __expf(sv[j2]-m_new);
        rs += p;
        Ps[(w*16+quad*4+e)*72 + j2*16 + l16] = __float2bfloat16(p);
      }
      #pragma unroll
      for (int off=1; off<16; off<<=1) rs += __shfl_xor(rs, off, 64);
      l_i[e] = l_i[e]*alpha + rs;
      m_i[e] = m_new;
      accO[0][e] *= alpha;
      accO[1][e] *= alpha;
    }
    asm volatile("s_waitcnt lgkmcnt(0)" ::: "memory");
    __builtin_amdgcn_sched_barrier(0);
    #pragma unroll
    for (int sh=0; sh<2; ++sh){
      short8 ap = *(short8*)&Ps[(w*16+l16)*72 + sh*32 + quad*8];
      #pragma unroll
      for (int dh=0; dh<2; ++dh){
        short8 bv = *(short8*)&Vt[cur][(dh*16+l16)*72 + sh*32 + quad*8];
        accO[dh] = __builtin_amdgcn_mfma_f32_16x16x32_bf16(ap, bv, accO[dh], 0,0,0);
      }
    }
    if (pre){
      #pragma unroll
      for (int q=0;q<8;q++){
        short tmp = vpre[q];
        Vt[nxt][(spos*8+q)*72 + srow] = *(bf16*)&tmp;
      }
    }
  }
  #pragma unroll
  for (int e=0;e<4;e++){
    float inv = 1.0f/l_i[e];
    int t = t0 + w*16 + quad*4 + e;
    bf16* op = o + ((size_t)(b*512+t))*256 + h*32 + l16;
    op[0]  = __float2bfloat16(accO[0][e]*inv);
    op[16] = __float2bfloat16(accO[1][e]*inv);
  }
}

// ------- standalone fused spatial attention (full-K dbuf, 256 thr) ---------
__global__ __launch_bounds__(256) void spatial_fused(
    const bf16* __restrict__ qk, float* __restrict__ out1,
    bf16* __restrict__ swB){
  int ct = blockIdx.x & 15, b = blockIdx.x >> 4;
  int tid = threadIdx.x;
  int w = tid>>6, lane = tid&63, quad = lane>>4, l16 = lane&15;
  __shared__ __align__(16) bf16 Qall[16*512];
  __shared__ __align__(16) bf16 Ks[2][256*64];
  __shared__ float redM[4][16], redS2[4][16];
  const bf16* qbase = qk + ((size_t)(b*256 + ct*16))*1024;
  #pragma unroll
  for (int c=0;c<4;c++){
    int ch = tid + c*256;
    int row = ch>>6, p = ch&63;
    gl_lds16(qbase + (size_t)row*1024 + ((p ^ (row&7))*8), &Qall[row*512 + p*8]);
  }
  auto stageK = [&](int h, int half){
    bf16* ks = Ks[half];
    #pragma unroll
    for (int c=0;c<8;c++){
      int ch = tid + c*256;
      int e = ch>>3, p = ch&7;
      gl_lds16(qk + ((size_t)(b*256 + e))*1024 + 512 + h*64 + ((p ^ (e&7))*8),
               &ks[e*64 + p*8]);
    }
  };
  stageK(0, 0);
  float fRes[4][4];
  #pragma unroll
  for (int j=0;j<4;j++)
    #pragma unroll
    for (int e=0;e<4;e++) fRes[j][e] = 0.0f;

  for (int h=0; h<8; ++h){
    __syncthreads();
    if (h+1 < 8) stageK(h+1, (h+1)&1);
    const bf16* kcur = Ks[h&1];
    f32x4 acc[4];
    #pragma unroll
    for (int j=0;j<4;j++) acc[j] = (f32x4){0.f,0.f,0.f,0.f};
    #pragma unroll
    for (int ki=0; ki<2; ++ki){
      int g = h*8 + ki*4 + quad;
      short8 aq = *(short8*)&Qall[l16*512 + ((g ^ (l16&7))*8)];
      #pragma unroll
      for (int j=0;j<4;j++){
        int e = w*64 + j*16 + l16;
        short8 bk = *(short8*)&kcur[e*64 + (((ki*4+quad) ^ (e&7))*8)];
        acc[j] = __builtin_amdgcn_mfma_f32_16x16x32_bf16(aq, bk, acc[j], 0,0,0);
      }
    }
    #pragma unroll
    for (int e=0;e<4;e++){
      float m = -3.0e38f;
      #pragma unroll
      for (int j=0;j<4;j++){
        float s = acc[j][e]*0.125f;
        acc[j][e] = s;
        m = fmaxf(m, s);
      }
      #pragma unroll
      for (int off=1; off<16; off<<=1) m = fmaxf(m, __shfl_xor(m, off, 16));
      if (l16==0) redM[w][quad*4+e] = m;
    }
    lgkm_barrier();
    #pragma unroll
    for (int e=0;e<4;e++){
      int r = quad*4+e;
      float m = fmaxf(fmaxf(redM[0][r],redM[1][r]), fmaxf(redM[2][r],redM[3][r]));
      float s = 0.0f;
      #pragma unroll
      for (int j=0;j<4;j++){
        float p = __expf(acc[j][e]-m);
        acc[j][e] = p; s += p;
      }
      #pragma unroll
      for (int off=1; off<16; off<<=1) s += __shfl_xor(s, off, 16);
      if (l16==0) redS2[w][r] = s;
    }
    lgkm_barrier();
    #pragma unroll
    for (int e=0;e<4;e++){
      int r = quad*4+e;
      float tot = redS2[0][r]+redS2[1][r]+redS2[2][r]+redS2[3][r];
      float inv = 0.125f/tot;
      #pragma unroll
      for (int j=0;j<4;j++) fRes[j][e] += acc[j][e]*inv;
    }
  }
  #pragma unroll
  for (int e=0;e<4;e++){
    int c = ct*16 + quad*4 + e;
    size_t rb = ((size_t)b*256 + c)*256;
    #pragma unroll
    for (int j=0;j<4;j++){
      int col = w*64 + j*16 + l16;
      out1[rb+col] = fRes[j][e];
      swB[rb+col]  = __float2bfloat16(fRes[j][e]);
    }
  }
}

extern "C" void kernel_launch(void* const* d_in, const int* in_sizes, int n_in,
                              void* d_out, int out_size, void* d_ws, size_t ws_size,
                              hipStream_t stream){
  (void)in_sizes; (void)n_in; (void)out_size; (void)ws_size;
  const float* x_T  = (const float*)d_in[0];
  const float* x_S  = (const float*)d_in[1];
  const float* Wq_t = (const float*)d_in[2];
  const float* Wk_t = (const float*)d_in[3];
  const float* Wv_t = (const float*)d_in[4];
  const float* Wo   = (const float*)d_in[5];
  const float* Wq_s = (const float*)d_in[6];
  const float* Wk_s = (const float*)d_in[7];
  const float* f1w1 = (const float*)d_in[8];
  const float* f1b1 = (const float*)d_in[9];
  const float* f1w2 = (const float*)d_in[10];
  const float* f1b2 = (const float*)d_in[11];
  const float* f2w1 = (const float*)d_in[12];
  const float* f2b1 = (const float*)d_in[13];
  const float* f2w2 = (const float*)d_in[14];
  const float* f2b2 = (const float*)d_in[15];
  const float* tl1w = (const float*)d_in[16];
  const float* tl1b = (const float*)d_in[17];
  const float* tl2w = (const float*)d_in[18];
  const float* tl2b = (const float*)d_in[19];
  const float* sl1w = (const float*)d_in[20];
  const float* sl1b = (const float*)d_in[21];
  const float* flw  = (const float*)d_in[22];
  const float* flb  = (const float*)d_in[23];

  float* ws = (float*)d_ws;
  size_t off = 0;
  bf16*  Wqkvb  = (bf16*)(ws + off); off += 768*256/2;
  bf16*  Wob    = (bf16*)(ws + off); off += 256*256/2;
  bf16*  f1w1b  = (bf16*)(ws + off); off += 1024*256/2;
  bf16*  f1w2b  = (bf16*)(ws + off); off += 256*1024/2;
  bf16*  f2w1b  = (bf16*)(ws + off); off += 1024*256/2;
  bf16*  f2w2b  = (bf16*)(ws + off); off += 256*1024/2;
  bf16*  WSb    = (bf16*)(ws + off); off += 1024*512/2;
  bf16*  bufHb  = (bf16*)(ws + off); off += (size_t)8192*256/2;
  bf16*  bufHSb = (bf16*)(ws + off); off += (size_t)4096*512/2;
  bf16*  bufQKVb= (bf16*)(ws + off); off += (size_t)8192*768/2;
  bf16*  bufOb  = (bf16*)(ws + off); off += (size_t)8192*256/2;
  bf16*  bufTOb = (bf16*)(ws + off); off += (size_t)8192*256/2;
  bf16*  swB    = (bf16*)(ws + off); off += (size_t)16*256*256/2;
  bf16*  qkB    = (bf16*)(ws + off); off += (size_t)4096*1024/2;
  float* bufTO  = ws + off; off += (size_t)8192*256;

  float* out0 = (float*)d_out;                      // [B,T,C]
  float* out1 = out0 + (size_t)16*512*256;          // spatial_weights [B,C,C]

  // 1. prologue: weight prep + LN(x_T) + LN(x_S)
  ProArgs pa;
  pa.wsrc[0]=Wq_t;  pa.wdst[0]=Wqkvb;
  pa.wsrc[1]=Wk_t;  pa.wdst[1]=Wqkvb+65536;
  pa.wsrc[2]=Wv_t;  pa.wdst[2]=Wqkvb+131072;
  pa.wsrc[3]=Wo;    pa.wdst[3]=Wob;
  pa.wsrc[4]=f1w1;  pa.wdst[4]=f1w1b;
  pa.wsrc[5]=f1w2;  pa.wdst[5]=f1w2b;
  pa.wsrc[6]=f2w1;  pa.wdst[6]=f2w1b;
  pa.wsrc[7]=f2w2;  pa.wdst[7]=f2w2b;
  pa.wsrc[8]=Wq_s;  pa.wdst[8]=WSb;
  pa.wsrc[9]=Wk_s;  pa.wdst[9]=WSb+262144;
  pa.xT=x_T; pa.xS=x_S; pa.tl1w=tl1w; pa.tl1b=tl1b;
  pa.sl1w=sl1w; pa.sl1b=sl1b; pa.hT=bufHb; pa.hS=bufHSb;
  prologue<<<4864,256,0,stream>>>(pa);

  // 2. dual <128,128>: qkv (384 tiles) + spatial projection (256 tiles)
  GArgs gq, gs;
  gq.A=bufHb;  gq.B=Wqkvb; gq.outF=nullptr; gq.outB=bufQKVb;
  gq.bias=nullptr; gq.resid=nullptr;
  gq.K=256; gq.lda=256; gq.ldb=256; gq.ldc=768; gq.flags=0; gq.ty=6;
  gs.A=bufHSb; gs.B=WSb;   gs.outF=nullptr; gs.outB=qkB;
  gs.bias=nullptr; gs.resid=nullptr;
  gs.K=512; gs.lda=512; gs.ldb=512; gs.ldc=1024; gs.flags=0; gs.ty=8;
  gemm_dual<<<640,256,0,stream>>>(gq, gs, 384);

  // 3. fused spatial attention (qkB L2-hot)
  spatial_fused<<<256,256,0,stream>>>(qkB, out1, swB);

  // 4. temporal causal flash attention -> bf16 o
  flash_mfma<<<dim3(8,8,16),256,0,stream>>>(bufQKVb, bufOb);

  // 5. lnffn1: x = o@Wo^T + x_T ; h2 = LN(x) ; TO = relu(h2@w1^T+b1)@w2^T + b2 + x
  LnFfnArgs la1;
  la1.A=bufOb; la1.Bm=Wob; la1.resid0=x_T; la1.lnw=tl2w; la1.lnb=tl2b;
  la1.W1=f1w1b; la1.B1=f1b1; la1.W2=f1w2b; la1.B2=f1b2;
  la1.outF=bufTO; la1.outB=bufTOb;
  la1.sA=0; la1.sB=0; la1.sR=0; la1.sO=0;
  lnffn<<<dim3(256,1,1),1024,0,stream>>>(la1);

  // 6. lnffn2: x2 = TO@sw[b]^T + TO ; h3 = LN(x2) ; out = relu(h3@w1+b1)@w2 + b2 + x2
  LnFfnArgs la2;
  la2.A=bufTOb; la2.Bm=swB; la2.resid0=bufTO; la2.lnw=flw; la2.lnb=flb;
  la2.W1=f2w1b; la2.B1=f2b1; la2.W2=f2w2b; la2.B2=f2b2;
  la2.outF=out0; la2.outB=nullptr;
  la2.sA=131072; la2.sB=65536; la2.sR=131072; la2.sO=131072;
  lnffn<<<dim3(16,1,16),1024,0,stream>>>(la2);
}

// Round 12
// 264.951 us; speedup vs baseline: 1.2897x; 1.2897x over previous
//
#include <hip/hip_runtime.h>
#include <hip/hip_bf16.h>

typedef __hip_bfloat16 bf16;
typedef __attribute__((ext_vector_type(8))) short short8;
typedef __attribute__((ext_vector_type(4))) float f32x4;

#define F_BIAS 1
#define F_RELU 2
#define F_RES  4

__device__ __forceinline__ void st_out(float* p, float v){ *p = v; }
__device__ __forceinline__ void st_out(bf16* p, float v){ *p = __float2bfloat16(v); }
__device__ __forceinline__ short f2bs(float f){
  bf16 h = __float2bfloat16(f);
  return *reinterpret_cast<short*>(&h);
}

// async global->LDS, 16 B per lane (linear LDS dest, pre-swizzled global src).
__device__ __forceinline__ void gl_lds16(const void* g, void* l){
  __builtin_amdgcn_global_load_lds(
      (const __attribute__((address_space(1))) void*)g,
      (__attribute__((address_space(3))) void*)l, 16, 0, 0);
}

// LDS-only barrier: orders ds ops, leaves global_load_lds (vmcnt) in flight.
__device__ __forceinline__ void lgkm_barrier(){
  asm volatile("s_waitcnt lgkmcnt(0)" ::: "memory");
  __builtin_amdgcn_s_barrier();
}

// ------------- prologue: weight prep (+fragment pack) + LN(x_T/x_S) --------
// Segs 3..7 (Wo, f1w1, f1w2, f2w1, f2w2) are packed MFMA-fragment-major:
// fragment (tn,tk) of W[N,K] = rows tn*16..+16, k tk*32..+32; stored as 512
// contiguous shorts at ((tn*(K/32)+tk)*64 + lane)*8, lane = quad*16+l16,
// holding W[tn*16+l16][tk*32+quad*8 .. +8]. A wave's fragment load is then
// one coalesced 1KB read instead of 64 scattered cache lines.
struct ProArgs {
  const float* wsrc[10];
  bf16* wdst[10];
  const float *xT, *xS, *tl1w, *tl1b, *sl1w, *sl1b;
  bf16 *hT, *hS;
};

template<int RL>
__device__ __forceinline__ void wave_ln(bf16* __restrict__ dst,
    const float* __restrict__ src, const float* __restrict__ w,
    const float* __restrict__ bvec, int row){
  int lane = threadIdx.x & 63;
  const float* s = src + (size_t)row*RL;
  float4 v0 = *(const float4*)(s + lane*4);
  float4 v1 = {0.f,0.f,0.f,0.f};
  float sum = v0.x+v0.y+v0.z+v0.w;
  float sq  = v0.x*v0.x+v0.y*v0.y+v0.z*v0.z+v0.w*v0.w;
  if (RL == 512){
    v1 = *(const float4*)(s + 256 + lane*4);
    sum += v1.x+v1.y+v1.z+v1.w;
    sq  += v1.x*v1.x+v1.y*v1.y+v1.z*v1.z+v1.w*v1.w;
  }
  #pragma unroll
  for (int off=32; off; off>>=1){
    sum += __shfl_xor(sum, off, 64);
    sq  += __shfl_xor(sq , off, 64);
  }
  const float inv = 1.0f/(float)RL;
  float mean = sum*inv;
  float rstd = rsqrtf(sq*inv - mean*mean + 1e-6f);
  float4 w0 = *(const float4*)(w + lane*4);
  float4 b0 = *(const float4*)(bvec + lane*4);
  bf16* d = dst + (size_t)row*RL;
  short4 o;
  o.x = f2bs((v0.x-mean)*rstd*w0.x + b0.x);
  o.y = f2bs((v0.y-mean)*rstd*w0.y + b0.y);
  o.z = f2bs((v0.z-mean)*rstd*w0.z + b0.z);
  o.w = f2bs((v0.w-mean)*rstd*w0.w + b0.w);
  *(short4*)((short*)d + lane*4) = o;
  if (RL == 512){
    float4 w1 = *(const float4*)(w + 256 + lane*4);
    float4 b1 = *(const float4*)(bvec + 256 + lane*4);
    short4 o1;
    o1.x = f2bs((v1.x-mean)*rstd*w1.x + b1.x);
    o1.y = f2bs((v1.y-mean)*rstd*w1.y + b1.y);
    o1.z = f2bs((v1.z-mean)*rstd*w1.z + b1.z);
    o1.w = f2bs((v1.w-mean)*rstd*w1.w + b1.w);
    *(short4*)((short*)d + 256 + lane*4) = o1;
  }
}

__global__ __launch_bounds__(256) void prologue(ProArgs a){
  int blk = blockIdx.x;
  int wid = threadIdx.x >> 6;
  if (blk < 1792){
    int v = blk*256 + threadIdx.x;
    int e = v*4;
    int seg = (e>=65536)+(e>=131072)+(e>=196608)+(e>=262144)+(e>=524288)
            + (e>=786432)+(e>=1048576)+(e>=1310720)+(e>=1572864);
    const int starts[10] = {0,65536,131072,196608,262144,524288,786432,
                            1048576,1310720,1572864};
    int off = e - starts[seg];
    float4 f = *(const float4*)(a.wsrc[seg] + off);
    short4 o;
    o.x = f2bs(f.x); o.y = f2bs(f.y); o.z = f2bs(f.z); o.w = f2bs(f.w);
    if (seg >= 3 && seg <= 7){
      // fragment-major pack; ld = K of the matrix (256 or 1024)
      int ldlog = (seg==5 || seg==7) ? 10 : 8;
      int r  = off >> ldlog;
      int c  = off & ((1<<ldlog)-1);
      int tn = r >> 4, lr = r & 15;
      int tk = c >> 5, qd = (c>>3)&3, b = c&7;
      int nkt = 1 << (ldlog-5);
      int dst = (((tn*nkt + tk)*64) + qd*16 + lr)*8 + b;
      *(short4*)((short*)a.wdst[seg] + dst) = o;
    } else {
      *(short4*)((short*)a.wdst[seg] + off) = o;
    }
  } else if (blk < 1792 + 2048){
    wave_ln<256>(a.hT, a.xT, a.tl1w, a.tl1b, (blk-1792)*4 + wid);
  } else {
    wave_ln<512>(a.hS, a.xS, a.sl1w, a.sl1b, (blk-3840)*4 + wid);
  }
}

// -- MFMA bf16 GEMM body (256 thr): dbuf, barrier at TOP ---------------------
template<int BM, int BN, int BK>
__device__ __forceinline__ void gemm_body(
    short* __restrict__ AsB, short* __restrict__ BsB,
    const bf16* __restrict__ A, const bf16* __restrict__ B,
    float* __restrict__ outF, bf16* __restrict__ outB,
    const float* __restrict__ bias, const float* __restrict__ resid,
    int K, int lda, int ldb, int ldc, int flags, int m0, int n0){
  int tid = threadIdx.x;
  int w = tid>>6, lane = tid&63, quad = lane>>4, l16 = lane&15;
  constexpr int MF  = BM/32;
  constexpr int NF  = BN/32;
  constexpr int CPR = BK/8;
  constexpr int CA  = BM*CPR/256;
  constexpr int CB  = BN*CPR/256;
  int wm = (w>>1)*(BM/2), wn = (w&1)*(BN/2);
  f32x4 acc[MF][NF];
  #pragma unroll
  for (int r=0;r<MF;r++)
    #pragma unroll
    for (int j=0;j<NF;j++)
      acc[r][j] = (f32x4){0.f,0.f,0.f,0.f};

  auto stage = [&](int k0, int half){
    short* as = AsB + half*(BM*BK);
    short* bs = BsB + half*(BN*BK);
    #pragma unroll
    for (int c=0;c<CA;c++){
      int ch = tid + c*256;
      int row = ch / CPR, p = ch % CPR;
      gl_lds16(A + (size_t)(m0+row)*lda + k0 + ((p ^ (row&(CPR-1)))*8),
               &as[row*BK + p*8]);
    }
    #pragma unroll
    for (int c=0;c<CB;c++){
      int ch = tid + c*256;
      int row = ch / CPR, p = ch % CPR;
      gl_lds16(B + (size_t)(n0+row)*ldb + k0 + ((p ^ (row&(CPR-1)))*8),
               &bs[row*BK + p*8]);
    }
  };

  stage(0, 0);
  int nk = K / BK;
  for (int t = 0; t < nk; ++t){
    __syncthreads();
    if (t+1 < nk) stage((t+1)*BK, (t+1)&1);
    const short* as = AsB + (t&1)*(BM*BK);
    const short* bs = BsB + (t&1)*(BN*BK);
    #pragma unroll
    for (int ks=0; ks<BK/32; ++ks){
      short8 af[MF], bfr[NF];
      #pragma unroll
      for (int r=0;r<MF;r++){
        int rr = wm + r*16 + l16;
        af[r] = *(short8*)&as[rr*BK + (((ks*4+quad) ^ (rr&(CPR-1)))*8)];
      }
      #pragma unroll
      for (int j=0;j<NF;j++){
        int rr = wn + j*16 + l16;
        bfr[j] = *(short8*)&bs[rr*BK + (((ks*4+quad) ^ (rr&(CPR-1)))*8)];
      }
      #pragma unroll
      for (int r=0;r<MF;r++)
        #pragma unroll
        for (int j=0;j<NF;j++)
          acc[r][j] = __builtin_amdgcn_mfma_f32_16x16x32_bf16(af[r], bfr[j], acc[r][j], 0,0,0);
    }
  }
  #pragma unroll
  for (int r=0;r<MF;r++){
    int mb = m0 + wm + r*16 + quad*4;
    #pragma unroll
    for (int j=0;j<NF;j++){
      int n = n0 + wn + j*16 + l16;
      float bv = (flags & F_BIAS) ? bias[n] : 0.0f;
      #pragma unroll
      for (int e=0;e<4;e++){
        float v = acc[r][j][e] + bv;
        if (flags & F_RELU) v = fmaxf(v, 0.0f);
        long long idx = (long long)(mb+e)*ldc + n;
        if (flags & F_RES) v += resid[idx];
        if (outF) outF[idx] = v;
        if (outB) st_out(outB + idx, v);
      }
    }
  }
}

// ---- dual GEMM: two independent <128,128> GEMMs in one launch (1-D grid) ---
struct GArgs {
  const bf16 *A, *B;
  float* outF; bf16* outB;
  const float *bias, *resid;
  int K, lda, ldb, ldc, flags, ty;
};
__global__ __launch_bounds__(256) void gemm_dual(GArgs g0, GArgs g1, int n0){
  __shared__ __align__(16) short As[2*128*64];
  __shared__ __align__(16) short Bs[2*128*64];
  int id = blockIdx.x;
  bool first = id < n0;
  const GArgs& g = first ? g0 : g1;
  int t = first ? id : id - n0;
  int bx = t / g.ty, by = t - bx*g.ty;
  gemm_body<128,128,64>(As, Bs, g.A, g.B, g.outF, g.outB, g.bias, g.resid,
                        g.K, g.lda, g.ldb, g.ldc, g.flags, bx*128, by*128);
}

// ---- lnffn v4: 512 thr; weights read as PACKED fragments (coalesced 1KB) --
// x = A@Bm^T + resid ; h = LN(x) ; out = relu(h@W1^T+b1)@W2^T + b2 + x
// x register-carried; Hin/Hs LDS-only (80 KB); 3 barriers total.
struct LnFfnArgs {
  const bf16 *A;        // [*,256] bf16 GEMM A (row-major)
  const bf16 *Bm;       // [256,256]: packed (Wob) or row-major (swB)
  int bmPacked;
  const float *resid0;  // f32 resid for x
  const float *lnw, *lnb;
  const bf16 *W1; const float *B1;   // W1 packed frags; [1024]
  const bf16 *W2; const float *B2;   // W2 packed frags; [256]
  float *outF; bf16 *outB;
  long long sA, sB, sR, sO;          // per-blockIdx.z element strides
};

__global__ __launch_bounds__(512) void lnffn(LnFfnArgs a){
  __shared__ __align__(16) short Hin[32*256];    // 16 KB (XOR g^row)
  __shared__ __align__(16) short Hs[32*1024];    // 64 KB (XOR g^(row&7))
  float (*redS)[32] = (float(*)[32])Hs;          // overlay (dead until phase A)
  float (*redQ)[32] = (float(*)[32])(Hs + 512);
  int bz = blockIdx.z;
  const bf16* A  = a.A  + (size_t)bz*a.sA;
  const bf16* Bm = a.Bm + (size_t)bz*a.sB;
  long long rbase = (long long)bz*a.sR;
  long long obase = (long long)bz*a.sO;
  int tid = threadIdx.x;
  int w = tid>>6, lane = tid&63, quad = lane>>4, l16 = lane&15;
  int m0 = blockIdx.x*32;

  // ------ phase 0: x = A@Bm^T (K=256); wave = 32 rows x 32 cols ------------
  f32x4 acc0[2][2];
  #pragma unroll
  for (int r=0;r<2;r++)
    #pragma unroll
    for (int j=0;j<2;j++) acc0[r][j] = (f32x4){0.f,0.f,0.f,0.f};
  #pragma unroll
  for (int ks=0; ks<8; ++ks){
    short8 af[2], bk[2];
    #pragma unroll
    for (int r=0;r<2;r++)
      af[r] = *(const short8*)(A + (size_t)(m0 + r*16 + l16)*256 + ks*32 + quad*8);
    #pragma unroll
    for (int j=0;j<2;j++){
      if (a.bmPacked){
        int tile = w*2 + j;                       // col tile 0..15
        bk[j] = *(const short8*)(Bm + ((size_t)(tile*8 + ks)*64 + lane)*8);
      } else {
        bk[j] = *(const short8*)(Bm + (size_t)(w*32 + j*16 + l16)*256 + ks*32 + quad*8);
      }
    }
    #pragma unroll
    for (int r=0;r<2;r++)
      #pragma unroll
      for (int j=0;j<2;j++)
        acc0[r][j] = __builtin_amdgcn_mfma_f32_16x16x32_bf16(af[r], bk[j], acc0[r][j], 0,0,0);
  }
  // resid add + per-row LN statistics
  #pragma unroll
  for (int r=0;r<2;r++)
    #pragma unroll
    for (int e=0;e<4;e++){
      int row = r*16 + quad*4 + e;
      float s = 0.f, q2 = 0.f;
      #pragma unroll
      for (int j=0;j<2;j++){
        float v = acc0[r][j][e] +
                  a.resid0[rbase + (long long)(m0+row)*256 + w*32 + j*16 + l16];
        acc0[r][j][e] = v;               // x stays in registers
        s += v; q2 += v*v;
      }
      #pragma unroll
      for (int off=1; off<16; off<<=1){
        s  += __shfl_xor(s , off, 16);
        q2 += __shfl_xor(q2, off, 16);
      }
      if (l16==0){ redS[w][row] = s; redQ[w][row] = q2; }
    }
  __syncthreads();
  #pragma unroll
  for (int r=0;r<2;r++)
    #pragma unroll
    for (int e=0;e<4;e++){
      int row = r*16 + quad*4 + e;
      float tot = 0.f, tq = 0.f;
      #pragma unroll
      for (int ww=0; ww<8; ww++){ tot += redS[ww][row]; tq += redQ[ww][row]; }
      float mean = tot * (1.0f/256.0f);
      float var  = tq * (1.0f/256.0f) - mean*mean;
      float rstd = rsqrtf(var + 1e-6f);
      #pragma unroll
      for (int j=0;j<2;j++){
        int col = w*32 + j*16 + l16;
        float h = (acc0[r][j][e]-mean)*rstd*a.lnw[col] + a.lnb[col];
        int g = col >> 3;
        Hin[row*256 + ((g ^ row)*8) + (col&7)] = f2bs(h);
      }
    }
  __syncthreads();                     // Hin visible; redS region now dead

  // ------ phase A: H = relu(h@W1^T + b1) -> Hs; W1 packed frags ------------
  for (int hc=0; hc<2; ++hc){
    f32x4 acc1[2][4];
    #pragma unroll
    for (int r=0;r<2;r++)
      #pragma unroll
      for (int j=0;j<4;j++) acc1[r][j] = (f32x4){0.f,0.f,0.f,0.f};
    #pragma unroll
    for (int ks=0; ks<8; ++ks){
      short8 af[2], bk[4];
      #pragma unroll
      for (int r=0;r<2;r++){
        int rr = r*16 + l16;
        int kk = ks*4 + quad;
        af[r] = *(short8*)&Hin[rr*256 + ((kk ^ rr)*8)];
      }
      #pragma unroll
      for (int j=0;j<4;j++){
        int ht = w*8 + hc*4 + j;                  // hidden tile 0..63
        bk[j] = *(const short8*)(a.W1 + ((size_t)(ht*8 + ks)*64 + lane)*8);
      }
      #pragma unroll
      for (int r=0;r<2;r++)
        #pragma unroll
        for (int j=0;j<4;j++)
          acc1[r][j] = __builtin_amdgcn_mfma_f32_16x16x32_bf16(af[r], bk[j], acc1[r][j], 0,0,0);
    }
    #pragma unroll
    for (int r=0;r<2;r++)
      #pragma unroll
      for (int j=0;j<4;j++)
        #pragma unroll
        for (int e=0;e<4;e++){
          int row = r*16 + quad*4 + e;
          int col = w*128 + hc*64 + j*16 + l16;
          float v = fmaxf(acc1[r][j][e] + a.B1[col], 0.0f);
          int g = col>>3;
          Hs[row*1024 + ((g ^ (row&7))*8) + (col&7)] = f2bs(v);
        }
  }
  __syncthreads();                     // Hs visible to all waves

  // ------ phase B: out = H@W2^T + b2 + x; W2 packed frags ------------------
  f32x4 accB[2][2];
  #pragma unroll
  for (int r=0;r<2;r++)
    #pragma unroll
    for (int j=0;j<2;j++) accB[r][j] = (f32x4){0.f,0.f,0.f,0.f};
  #pragma unroll 8
  for (int ks=0; ks<32; ++ks){
    short8 af[2], bk[2];
    #pragma unroll
    for (int r=0;r<2;r++){
      int rr = r*16 + l16;
      int kk = ks*4 + quad;
      af[r] = *(short8*)&Hs[rr*1024 + ((kk ^ (rr&7))*8)];
    }
    #pragma unroll
    for (int j=0;j<2;j++){
      int nt = w*2 + j;                           // output-col tile 0..15
      bk[j] = *(const short8*)(a.W2 + ((size_t)(nt*32 + ks)*64 + lane)*8);
    }
    #pragma unroll
    for (int r=0;r<2;r++)
      #pragma unroll
      for (int j=0;j<2;j++)
        accB[r][j] = __builtin_amdgcn_mfma_f32_16x16x32_bf16(af[r], bk[j], accB[r][j], 0,0,0);
  }
  #pragma unroll
  for (int r=0;r<2;r++)
    #pragma unroll
    for (int j=0;j<2;j++){
      int n = w*32 + j*16 + l16;
      float bv = a.B2[n];
      #pragma unroll
      for (int e=0;e<4;e++){
        int row = r*16 + quad*4 + e;
        long long idx = obase + (long long)(m0+row)*256 + n;
        float v = accB[r][j][e] + bv + acc0[r][j][e];   // register-carried x
        a.outF[idx] = v;
        if (a.outB) st_out(a.outB + idx, v);
      }
    }
}

// ---------------- MFMA flash temporal causal attention ----------------
__device__ __forceinline__ int fsw(int row){ return (row>>1)&3; }
__global__ __launch_bounds__(256) void flash_mfma(
    const bf16* __restrict__ qkv, bf16* __restrict__ o){
  int qt = (int)gridDim.x - 1 - (int)blockIdx.x;   // longest blocks first
  int h = blockIdx.y, b = blockIdx.z;
  int tid = threadIdx.x;
  int w = tid>>6, lane = tid&63, quad = lane>>4, l16 = lane&15;
  __shared__ __align__(16) bf16 Qs[64*32];
  __shared__ __align__(16) bf16 Ks[2][64*32];
  __shared__ __align__(16) bf16 Vt[2][32*72];
  __shared__ __align__(16) bf16 Ps[64*72];
  const bf16* base = qkv + (size_t)b*512*768;
  int t0 = qt*64;
  int srow = tid>>2, spos = tid&3;
  gl_lds16(base + (size_t)(t0+srow)*768 + h*32 + ((spos ^ fsw(srow))*8),
           &Qs[srow*32 + spos*8]);
  {
    const bf16* rp = base + (size_t)srow*768 + h*32;
    gl_lds16(rp + 256 + ((spos ^ fsw(srow))*8), &Ks[0][srow*32 + spos*8]);
    short8 v = *(const short8*)(rp + 512 + spos*8);
    #pragma unroll
    for (int q=0;q<8;q++){
      short tmp = v[q];
      Vt[0][(spos*8+q)*72 + srow] = *(bf16*)&tmp;
    }
  }
  f32x4 accO[2];
  accO[0] = (f32x4){0.f,0.f,0.f,0.f};
  accO[1] = (f32x4){0.f,0.f,0.f,0.f};
  float m_i[4], l_i[4];
  #pragma unroll
  for (int e=0;e<4;e++){ m_i[e] = -3.0e38f; l_i[e] = 0.0f; }
  const float scale = 0.17677669529663687f;
  __syncthreads();
  int rq = w*16 + l16;
  short8 aq = *(short8*)&Qs[rq*32 + ((quad ^ fsw(rq))*8)];

  for (int kt = 0; kt <= qt; ++kt){
    if (kt) __syncthreads();
    int cur = kt&1, nxt = cur^1;
    bool pre = (kt < qt);
    short8 vpre;
    if (pre){
      const bf16* rp = base + (size_t)((kt+1)*64 + srow)*768 + h*32;
      gl_lds16(rp + 256 + ((spos ^ fsw(srow))*8), &Ks[nxt][srow*32 + spos*8]);
      vpre = *(const short8*)(rp + 512 + spos*8);
    }
    f32x4 S[4];
    #pragma unroll
    for (int j2=0;j2<4;j2++){
      int rk = j2*16 + l16;
      short8 bk = *(short8*)&Ks[cur][rk*32 + ((quad ^ fsw(rk))*8)];
      S[j2] = __builtin_amdgcn_mfma_f32_16x16x32_bf16(aq, bk,
                (f32x4){0.f,0.f,0.f,0.f}, 0,0,0);
    }
    bool diag = (kt == qt);
    int s0 = kt*64;
    int qrow_base = t0 + w*16 + quad*4;
    #pragma unroll
    for (int e=0;e<4;e++){
      float sv[4];
      #pragma unroll
      for (int j2=0;j2<4;j2++){
        float x = S[j2][e]*scale;
        if (diag && (s0 + j2*16 + l16 > qrow_base + e)) x = -3.0e38f;
        sv[j2] = x;
      }
      float mx = fmaxf(fmaxf(sv[0],sv[1]), fmaxf(sv[2],sv[3]));
      #pragma unroll
      for (int off=1; off<16; off<<=1) mx = fmaxf(mx, __shfl_xor(mx, off, 64));
      float m_new = fmaxf(m_i[e], mx);
      float alpha = __expf(m_i[e]-m_new);
      float rs = 0.0f;
      #pragma unroll
      for (int j2=0;j2<4;j2++){
        float p = __expf(sv[j2]-m_new);
        rs += p;
        Ps[(w*16+quad*4+e)*72 + j2*16 + l16] = __float2bfloat16(p);
      }
      #pragma unroll
      for (int off=1; off<16; off<<=1) rs += __shfl_xor(rs, off, 64);
      l_i[e] = l_i[e]*alpha + rs;
      m_i[e] = m_new;
      accO[0][e] *= alpha;
      accO[1][e] *= alpha;
    }
    asm volatile("s_waitcnt lgkmcnt(0)" ::: "memory");
    __builtin_amdgcn_sched_barrier(0);
    #pragma unroll
    for (int sh=0; sh<2; ++sh){
      short8 ap = *(short8*)&Ps[(w*16+l16)*72 + sh*32 + quad*8];
      #pragma unroll
      for (int dh=0; dh<2; ++dh){
        short8 bv = *(short8*)&Vt[cur][(dh*16+l16)*72 + sh*32 + quad*8];
        accO[dh] = __builtin_amdgcn_mfma_f32_16x16x32_bf16(ap, bv, accO[dh], 0,0,0);
      }
    }
    if (pre){
      #pragma unroll
      for (int q=0;q<8;q++){
        short tmp = vpre[q];
        Vt[nxt][(spos*8+q)*72 + srow] = *(bf16*)&tmp;
      }
    }
  }
  #pragma unroll
  for (int e=0;e<4;e++){
    float inv = 1.0f/l_i[e];
    int t = t0 + w*16 + quad*4 + e;
    bf16* op = o + ((size_t)(b*512+t))*256 + h*32 + l16;
    op[0]  = __float2bfloat16(accO[0][e]*inv);
    op[16] = __float2bfloat16(accO[1][e]*inv);
  }
}

// ------- standalone fused spatial attention (full-K dbuf, 256 thr) ---------
__global__ __launch_bounds__(256) void spatial_fused(
    const bf16* __restrict__ qk, float* __restrict__ out1,
    bf16* __restrict__ swB){
  int ct = blockIdx.x & 15, b = blockIdx.x >> 4;
  int tid = threadIdx.x;
  int w = tid>>6, lane = tid&63, quad = lane>>4, l16 = lane&15;
  __shared__ __align__(16) bf16 Qall[16*512];
  __shared__ __align__(16) bf16 Ks[2][256*64];
  __shared__ float redM[4][16], redS2[4][16];
  const bf16* qbase = qk + ((size_t)(b*256 + ct*16))*1024;
  #pragma unroll
  for (int c=0;c<4;c++){
    int ch = tid + c*256;
    int row = ch>>6, p = ch&63;
    gl_lds16(qbase + (size_t)row*1024 + ((p ^ (row&7))*8), &Qall[row*512 + p*8]);
  }
  auto stageK = [&](int h, int half){
    bf16* ks = Ks[half];
    #pragma unroll
    for (int c=0;c<8;c++){
      int ch = tid + c*256;
      int e = ch>>3, p = ch&7;
      gl_lds16(qk + ((size_t)(b*256 + e))*1024 + 512 + h*64 + ((p ^ (e&7))*8),
               &ks[e*64 + p*8]);
    }
  };
  stageK(0, 0);
  float fRes[4][4];
  #pragma unroll
  for (int j=0;j<4;j++)
    #pragma unroll
    for (int e=0;e<4;e++) fRes[j][e] = 0.0f;

  for (int h=0; h<8; ++h){
    __syncthreads();
    if (h+1 < 8) stageK(h+1, (h+1)&1);
    const bf16* kcur = Ks[h&1];
    f32x4 acc[4];
    #pragma unroll
    for (int j=0;j<4;j++) acc[j] = (f32x4){0.f,0.f,0.f,0.f};
    #pragma unroll
    for (int ki=0; ki<2; ++ki){
      int g = h*8 + ki*4 + quad;
      short8 aq = *(short8*)&Qall[l16*512 + ((g ^ (l16&7))*8)];
      #pragma unroll
      for (int j=0;j<4;j++){
        int e = w*64 + j*16 + l16;
        short8 bk = *(short8*)&kcur[e*64 + (((ki*4+quad) ^ (e&7))*8)];
        acc[j] = __builtin_amdgcn_mfma_f32_16x16x32_bf16(aq, bk, acc[j], 0,0,0);
      }
    }
    #pragma unroll
    for (int e=0;e<4;e++){
      float m = -3.0e38f;
      #pragma unroll
      for (int j=0;j<4;j++){
        float s = acc[j][e]*0.125f;
        acc[j][e] = s;
        m = fmaxf(m, s);
      }
      #pragma unroll
      for (int off=1; off<16; off<<=1) m = fmaxf(m, __shfl_xor(m, off, 16));
      if (l16==0) redM[w][quad*4+e] = m;
    }
    lgkm_barrier();
    #pragma unroll
    for (int e=0;e<4;e++){
      int r = quad*4+e;
      float m = fmaxf(fmaxf(redM[0][r],redM[1][r]), fmaxf(redM[2][r],redM[3][r]));
      float s = 0.0f;
      #pragma unroll
      for (int j=0;j<4;j++){
        float p = __expf(acc[j][e]-m);
        acc[j][e] = p; s += p;
      }
      #pragma unroll
      for (int off=1; off<16; off<<=1) s += __shfl_xor(s, off, 16);
      if (l16==0) redS2[w][r] = s;
    }
    lgkm_barrier();
    #pragma unroll
    for (int e=0;e<4;e++){
      int r = quad*4+e;
      float tot = redS2[0][r]+redS2[1][r]+redS2[2][r]+redS2[3][r];
      float inv = 0.125f/tot;
      #pragma unroll
      for (int j=0;j<4;j++) fRes[j][e] += acc[j][e]*inv;
    }
  }
  #pragma unroll
  for (int e=0;e<4;e++){
    int c = ct*16 + quad*4 + e;
    size_t rb = ((size_t)b*256 + c)*256;
    #pragma unroll
    for (int j=0;j<4;j++){
      int col = w*64 + j*16 + l16;
      out1[rb+col] = fRes[j][e];
      swB[rb+col]  = __float2bfloat16(fRes[j][e]);
    }
  }
}

extern "C" void kernel_launch(void* const* d_in, const int* in_sizes, int n_in,
                              void* d_out, int out_size, void* d_ws, size_t ws_size,
                              hipStream_t stream){
  (void)in_sizes; (void)n_in; (void)out_size; (void)ws_size;
  const float* x_T  = (const float*)d_in[0];
  const float* x_S  = (const float*)d_in[1];
  const float* Wq_t = (const float*)d_in[2];
  const float* Wk_t = (const float*)d_in[3];
  const float* Wv_t = (const float*)d_in[4];
  const float* Wo   = (const float*)d_in[5];
  const float* Wq_s = (const float*)d_in[6];
  const float* Wk_s = (const float*)d_in[7];
  const float* f1w1 = (const float*)d_in[8];
  const float* f1b1 = (const float*)d_in[9];
  const float* f1w2 = (const float*)d_in[10];
  const float* f1b2 = (const float*)d_in[11];
  const float* f2w1 = (const float*)d_in[12];
  const float* f2b1 = (const float*)d_in[13];
  const float* f2w2 = (const float*)d_in[14];
  const float* f2b2 = (const float*)d_in[15];
  const float* tl1w = (const float*)d_in[16];
  const float* tl1b = (const float*)d_in[17];
  const float* tl2w = (const float*)d_in[18];
  const float* tl2b = (const float*)d_in[19];
  const float* sl1w = (const float*)d_in[20];
  const float* sl1b = (const float*)d_in[21];
  const float* flw  = (const float*)d_in[22];
  const float* flb  = (const float*)d_in[23];

  float* ws = (float*)d_ws;
  size_t off = 0;
  bf16*  Wqkvb  = (bf16*)(ws + off); off += 768*256/2;
  bf16*  Wob    = (bf16*)(ws + off); off += 256*256/2;
  bf16*  f1w1b  = (bf16*)(ws + off); off += 1024*256/2;
  bf16*  f1w2b  = (bf16*)(ws + off); off += 256*1024/2;
  bf16*  f2w1b  = (bf16*)(ws + off); off += 1024*256/2;
  bf16*  f2w2b  = (bf16*)(ws + off); off += 256*1024/2;
  bf16*  WSb    = (bf16*)(ws + off); off += 1024*512/2;
  bf16*  bufHb  = (bf16*)(ws + off); off += (size_t)8192*256/2;
  bf16*  bufHSb = (bf16*)(ws + off); off += (size_t)4096*512/2;
  bf16*  bufQKVb= (bf16*)(ws + off); off += (size_t)8192*768/2;
  bf16*  bufOb  = (bf16*)(ws + off); off += (size_t)8192*256/2;
  bf16*  bufTOb = (bf16*)(ws + off); off += (size_t)8192*256/2;
  bf16*  swB    = (bf16*)(ws + off); off += (size_t)16*256*256/2;
  bf16*  qkB    = (bf16*)(ws + off); off += (size_t)4096*1024/2;
  float* bufTO  = ws + off; off += (size_t)8192*256;

  float* out0 = (float*)d_out;                      // [B,T,C]
  float* out1 = out0 + (size_t)16*512*256;          // spatial_weights [B,C,C]

  // 1. prologue: weight prep (+frag pack for Wo/FFN weights) + LN
  ProArgs pa;
  pa.wsrc[0]=Wq_t;  pa.wdst[0]=Wqkvb;
  pa.wsrc[1]=Wk_t;  pa.wdst[1]=Wqkvb+65536;
  pa.wsrc[2]=Wv_t;  pa.wdst[2]=Wqkvb+131072;
  pa.wsrc[3]=Wo;    pa.wdst[3]=Wob;
  pa.wsrc[4]=f1w1;  pa.wdst[4]=f1w1b;
  pa.wsrc[5]=f1w2;  pa.wdst[5]=f1w2b;
  pa.wsrc[6]=f2w1;  pa.wdst[6]=f2w1b;
  pa.wsrc[7]=f2w2;  pa.wdst[7]=f2w2b;
  pa.wsrc[8]=Wq_s;  pa.wdst[8]=WSb;
  pa.wsrc[9]=Wk_s;  pa.wdst[9]=WSb+262144;
  pa.xT=x_T; pa.xS=x_S; pa.tl1w=tl1w; pa.tl1b=tl1b;
  pa.sl1w=sl1w; pa.sl1b=sl1b; pa.hT=bufHb; pa.hS=bufHSb;
  prologue<<<4864,256,0,stream>>>(pa);

  // 2. dual <128,128>: qkv (384 tiles) + spatial projection (256 tiles)
  GArgs gq, gs;
  gq.A=bufHb;  gq.B=Wqkvb; gq.outF=nullptr; gq.outB=bufQKVb;
  gq.bias=nullptr; gq.resid=nullptr;
  gq.K=256; gq.lda=256; gq.ldb=256; gq.ldc=768; gq.flags=0; gq.ty=6;
  gs.A=bufHSb; gs.B=WSb;   gs.outF=nullptr; gs.outB=qkB;
  gs.bias=nullptr; gs.resid=nullptr;
  gs.K=512; gs.lda=512; gs.ldb=512; gs.ldc=1024; gs.flags=0; gs.ty=8;
  gemm_dual<<<640,256,0,stream>>>(gq, gs, 384);

  // 3. fused spatial attention (qkB L2-hot)
  spatial_fused<<<256,256,0,stream>>>(qkB, out1, swB);

  // 4. temporal causal flash attention -> bf16 o
  flash_mfma<<<dim3(8,8,16),256,0,stream>>>(bufQKVb, bufOb);

  // 5. lnffn1: x = o@Wo^T + x_T ; h2 = LN(x) ; TO = relu(h2@w1^T+b1)@w2^T + b2 + x
  LnFfnArgs la1;
  la1.A=bufOb; la1.Bm=Wob; la1.bmPacked=1;
  la1.resid0=x_T; la1.lnw=tl2w; la1.lnb=tl2b;
  la1.W1=f1w1b; la1.B1=f1b1; la1.W2=f1w2b; la1.B2=f1b2;
  la1.outF=bufTO; la1.outB=bufTOb;
  la1.sA=0; la1.sB=0; la1.sR=0; la1.sO=0;
  lnffn<<<dim3(256,1,1),512,0,stream>>>(la1);

  // 6. lnffn2: x2 = TO@sw[b]^T + TO ; h3 = LN(x2) ; out = relu(h3@w1+b1)@w2 + b2 + x2
  LnFfnArgs la2;
  la2.A=bufTOb; la2.Bm=swB; la2.bmPacked=0;
  la2.resid0=bufTO; la2.lnw=flw; la2.lnb=flb;
  la2.W1=f2w1b; la2.B1=f2b1; la2.W2=f2w2b; la2.B2=f2b2;
  la2.outF=out0; la2.outB=nullptr;
  la2.sA=131072; la2.sB=65536; la2.sR=131072; la2.sO=131072;
  lnffn<<<dim3(16,1,16),512,0,stream>>>(la2);
}

// Round 13
// 254.746 us; speedup vs baseline: 1.3414x; 1.0401x over previous
//
#include <hip/hip_runtime.h>
#include <hip/hip_bf16.h>

typedef __hip_bfloat16 bf16;
typedef __attribute__((ext_vector_type(8))) short short8;
typedef __attribute__((ext_vector_type(4))) float f32x4;

#define F_BIAS 1
#define F_RELU 2
#define F_RES  4

__device__ __forceinline__ void st_out(float* p, float v){ *p = v; }
__device__ __forceinline__ void st_out(bf16* p, float v){ *p = __float2bfloat16(v); }
__device__ __forceinline__ short f2bs(float f){
  bf16 h = __float2bfloat16(f);
  return *reinterpret_cast<short*>(&h);
}

// async global->LDS, 16 B per lane (linear LDS dest, pre-swizzled global src).
__device__ __forceinline__ void gl_lds16(const void* g, void* l){
  __builtin_amdgcn_global_load_lds(
      (const __attribute__((address_space(1))) void*)g,
      (__attribute__((address_space(3))) void*)l, 16, 0, 0);
}

// LDS-only barrier: orders ds ops, leaves global_load_lds (vmcnt) in flight.
__device__ __forceinline__ void lgkm_barrier(){
  asm volatile("s_waitcnt lgkmcnt(0)" ::: "memory");
  __builtin_amdgcn_s_barrier();
}

// Fragment-major packed layout (shared by weights and activations):
// fragment (tr, tk) of M[R,K] = rows tr*16..+16, k tk*32..+32, stored as 512
// contiguous shorts at ((tr*(K/32)+tk)*64 + quad*16 + l16)*8 + b, holding
// M[tr*16+l16][tk*32+quad*8+b]. A wave's fragment load = one coalesced 1KB.

// ------------- prologue: weight prep (+fragment pack) + LN(x_T/x_S) --------
struct ProArgs {
  const float* wsrc[10];
  bf16* wdst[10];
  const float *xT, *xS, *tl1w, *tl1b, *sl1w, *sl1b;
  bf16 *hT, *hS;
};

template<int RL>
__device__ __forceinline__ void wave_ln(bf16* __restrict__ dst,
    const float* __restrict__ src, const float* __restrict__ w,
    const float* __restrict__ bvec, int row){
  int lane = threadIdx.x & 63;
  const float* s = src + (size_t)row*RL;
  float4 v0 = *(const float4*)(s + lane*4);
  float4 v1 = {0.f,0.f,0.f,0.f};
  float sum = v0.x+v0.y+v0.z+v0.w;
  float sq  = v0.x*v0.x+v0.y*v0.y+v0.z*v0.z+v0.w*v0.w;
  if (RL == 512){
    v1 = *(const float4*)(s + 256 + lane*4);
    sum += v1.x+v1.y+v1.z+v1.w;
    sq  += v1.x*v1.x+v1.y*v1.y+v1.z*v1.z+v1.w*v1.w;
  }
  #pragma unroll
  for (int off=32; off; off>>=1){
    sum += __shfl_xor(sum, off, 64);
    sq  += __shfl_xor(sq , off, 64);
  }
  const float inv = 1.0f/(float)RL;
  float mean = sum*inv;
  float rstd = rsqrtf(sq*inv - mean*mean + 1e-6f);
  float4 w0 = *(const float4*)(w + lane*4);
  float4 b0 = *(const float4*)(bvec + lane*4);
  bf16* d = dst + (size_t)row*RL;
  short4 o;
  o.x = f2bs((v0.x-mean)*rstd*w0.x + b0.x);
  o.y = f2bs((v0.y-mean)*rstd*w0.y + b0.y);
  o.z = f2bs((v0.z-mean)*rstd*w0.z + b0.z);
  o.w = f2bs((v0.w-mean)*rstd*w0.w + b0.w);
  *(short4*)((short*)d + lane*4) = o;
  if (RL == 512){
    float4 w1 = *(const float4*)(w + 256 + lane*4);
    float4 b1 = *(const float4*)(bvec + 256 + lane*4);
    short4 o1;
    o1.x = f2bs((v1.x-mean)*rstd*w1.x + b1.x);
    o1.y = f2bs((v1.y-mean)*rstd*w1.y + b1.y);
    o1.z = f2bs((v1.z-mean)*rstd*w1.z + b1.z);
    o1.w = f2bs((v1.w-mean)*rstd*w1.w + b1.w);
    *(short4*)((short*)d + 256 + lane*4) = o1;
  }
}

__global__ __launch_bounds__(256) void prologue(ProArgs a){
  int blk = blockIdx.x;
  int wid = threadIdx.x >> 6;
  if (blk < 1792){
    int v = blk*256 + threadIdx.x;
    int e = v*4;
    int seg = (e>=65536)+(e>=131072)+(e>=196608)+(e>=262144)+(e>=524288)
            + (e>=786432)+(e>=1048576)+(e>=1310720)+(e>=1572864);
    const int starts[10] = {0,65536,131072,196608,262144,524288,786432,
                            1048576,1310720,1572864};
    int off = e - starts[seg];
    float4 f = *(const float4*)(a.wsrc[seg] + off);
    short4 o;
    o.x = f2bs(f.x); o.y = f2bs(f.y); o.z = f2bs(f.z); o.w = f2bs(f.w);
    if (seg >= 3 && seg <= 7){
      // fragment-major pack; ld = K of the matrix (256 or 1024)
      int ldlog = (seg==5 || seg==7) ? 10 : 8;
      int r  = off >> ldlog;
      int c  = off & ((1<<ldlog)-1);
      int tn = r >> 4, lr = r & 15;
      int tk = c >> 5, qd = (c>>3)&3, b = c&7;
      int nkt = 1 << (ldlog-5);
      int dst = (((tn*nkt + tk)*64) + qd*16 + lr)*8 + b;
      *(short4*)((short*)a.wdst[seg] + dst) = o;
    } else {
      *(short4*)((short*)a.wdst[seg] + off) = o;
    }
  } else if (blk < 1792 + 2048){
    wave_ln<256>(a.hT, a.xT, a.tl1w, a.tl1b, (blk-1792)*4 + wid);
  } else {
    wave_ln<512>(a.hS, a.xS, a.sl1w, a.sl1b, (blk-3840)*4 + wid);
  }
}

// -- MFMA bf16 GEMM body (256 thr): dbuf, barrier at TOP ---------------------
template<int BM, int BN, int BK>
__device__ __forceinline__ void gemm_body(
    short* __restrict__ AsB, short* __restrict__ BsB,
    const bf16* __restrict__ A, const bf16* __restrict__ B,
    float* __restrict__ outF, bf16* __restrict__ outB,
    const float* __restrict__ bias, const float* __restrict__ resid,
    int K, int lda, int ldb, int ldc, int flags, int m0, int n0){
  int tid = threadIdx.x;
  int w = tid>>6, lane = tid&63, quad = lane>>4, l16 = lane&15;
  constexpr int MF  = BM/32;
  constexpr int NF  = BN/32;
  constexpr int CPR = BK/8;
  constexpr int CA  = BM*CPR/256;
  constexpr int CB  = BN*CPR/256;
  int wm = (w>>1)*(BM/2), wn = (w&1)*(BN/2);
  f32x4 acc[MF][NF];
  #pragma unroll
  for (int r=0;r<MF;r++)
    #pragma unroll
    for (int j=0;j<NF;j++)
      acc[r][j] = (f32x4){0.f,0.f,0.f,0.f};

  auto stage = [&](int k0, int half){
    short* as = AsB + half*(BM*BK);
    short* bs = BsB + half*(BN*BK);
    #pragma unroll
    for (int c=0;c<CA;c++){
      int ch = tid + c*256;
      int row = ch / CPR, p = ch % CPR;
      gl_lds16(A + (size_t)(m0+row)*lda + k0 + ((p ^ (row&(CPR-1)))*8),
               &as[row*BK + p*8]);
    }
    #pragma unroll
    for (int c=0;c<CB;c++){
      int ch = tid + c*256;
      int row = ch / CPR, p = ch % CPR;
      gl_lds16(B + (size_t)(n0+row)*ldb + k0 + ((p ^ (row&(CPR-1)))*8),
               &bs[row*BK + p*8]);
    }
  };

  stage(0, 0);
  int nk = K / BK;
  for (int t = 0; t < nk; ++t){
    __syncthreads();
    if (t+1 < nk) stage((t+1)*BK, (t+1)&1);
    const short* as = AsB + (t&1)*(BM*BK);
    const short* bs = BsB + (t&1)*(BN*BK);
    #pragma unroll
    for (int ks=0; ks<BK/32; ++ks){
      short8 af[MF], bfr[NF];
      #pragma unroll
      for (int r=0;r<MF;r++){
        int rr = wm + r*16 + l16;
        af[r] = *(short8*)&as[rr*BK + (((ks*4+quad) ^ (rr&(CPR-1)))*8)];
      }
      #pragma unroll
      for (int j=0;j<NF;j++){
        int rr = wn + j*16 + l16;
        bfr[j] = *(short8*)&bs[rr*BK + (((ks*4+quad) ^ (rr&(CPR-1)))*8)];
      }
      #pragma unroll
      for (int r=0;r<MF;r++)
        #pragma unroll
        for (int j=0;j<NF;j++)
          acc[r][j] = __builtin_amdgcn_mfma_f32_16x16x32_bf16(af[r], bfr[j], acc[r][j], 0,0,0);
    }
  }
  #pragma unroll
  for (int r=0;r<MF;r++){
    int mb = m0 + wm + r*16 + quad*4;
    #pragma unroll
    for (int j=0;j<NF;j++){
      int n = n0 + wn + j*16 + l16;
      float bv = (flags & F_BIAS) ? bias[n] : 0.0f;
      #pragma unroll
      for (int e=0;e<4;e++){
        float v = acc[r][j][e] + bv;
        if (flags & F_RELU) v = fmaxf(v, 0.0f);
        long long idx = (long long)(mb+e)*ldc + n;
        if (flags & F_RES) v += resid[idx];
        if (outF) outF[idx] = v;
        if (outB) st_out(outB + idx, v);
      }
    }
  }
}

// ---- dual GEMM: two independent <128,128> GEMMs in one launch (1-D grid) ---
struct GArgs {
  const bf16 *A, *B;
  float* outF; bf16* outB;
  const float *bias, *resid;
  int K, lda, ldb, ldc, flags, ty;
};
__global__ __launch_bounds__(256) void gemm_dual(GArgs g0, GArgs g1, int n0){
  __shared__ __align__(16) short As[2*128*64];
  __shared__ __align__(16) short Bs[2*128*64];
  int id = blockIdx.x;
  bool first = id < n0;
  const GArgs& g = first ? g0 : g1;
  int t = first ? id : id - n0;
  int bx = t / g.ty, by = t - bx*g.ty;
  gemm_body<128,128,64>(As, Bs, g.A, g.B, g.outF, g.outB, g.bias, g.resid,
                        g.K, g.lda, g.ldb, g.ldc, g.flags, bx*128, by*128);
}

// ---- lnffn v5: ALL global MFMA operands packed fragment-major (1KB loads) --
// x = A@Bm^T + resid ; h = LN(x) ; out = relu(h@W1^T+b1)@W2^T + b2 + x
// A packed (bufOb by flash / bufTOb by lnffn1), Bm packed (Wob by prologue /
// swB by spatial), W1/W2 packed by prologue. x register-carried; 80 KB LDS.
struct LnFfnArgs {
  const bf16 *A;        // packed frags, per-batch 512-row local tiling
  const bf16 *Bm;       // [256,256] packed frags
  const float *resid0;  // f32 resid for x (row-major)
  const float *lnw, *lnb;
  const bf16 *W1; const float *B1;   // W1 packed frags; [1024]
  const bf16 *W2; const float *B2;   // W2 packed frags; [256]
  float *outF; bf16 *outB;           // outB written PACKED (batch-local)
  long long sA, sB, sR, sO;          // per-blockIdx.z element strides
};

__global__ __launch_bounds__(512) void lnffn(LnFfnArgs a){
  __shared__ __align__(16) short Hin[32*256];    // 16 KB (XOR g^row)
  __shared__ __align__(16) short Hs[32*1024];    // 64 KB (XOR g^(row&7))
  float (*redS)[32] = (float(*)[32])Hs;          // overlay (dead until phase A)
  float (*redQ)[32] = (float(*)[32])(Hs + 512);
  int bz = blockIdx.z;
  const bf16* A  = a.A  + (size_t)bz*a.sA;
  const bf16* Bm = a.Bm + (size_t)bz*a.sB;
  long long rbase = (long long)bz*a.sR;
  long long obase = (long long)bz*a.sO;
  int tid = threadIdx.x;
  int w = tid>>6, lane = tid&63, quad = lane>>4, l16 = lane&15;
  int m0 = blockIdx.x*32;
  int mt0 = m0 >> 4;                   // first row-tile index (batch-local)

  // ------ phase 0: x = A@Bm^T (K=256); wave = 32 rows x 32 cols ------------
  f32x4 acc0[2][2];
  #pragma unroll
  for (int r=0;r<2;r++)
    #pragma unroll
    for (int j=0;j<2;j++) acc0[r][j] = (f32x4){0.f,0.f,0.f,0.f};
  #pragma unroll
  for (int ks=0; ks<8; ++ks){
    short8 af[2], bk[2];
    #pragma unroll
    for (int r=0;r<2;r++)
      af[r] = *(const short8*)(A + (((size_t)(mt0+r)*8 + ks)*64 + lane)*8);
    #pragma unroll
    for (int j=0;j<2;j++){
      int tile = w*2 + j;                         // col tile 0..15
      bk[j] = *(const short8*)(Bm + ((size_t)(tile*8 + ks)*64 + lane)*8);
    }
    #pragma unroll
    for (int r=0;r<2;r++)
      #pragma unroll
      for (int j=0;j<2;j++)
        acc0[r][j] = __builtin_amdgcn_mfma_f32_16x16x32_bf16(af[r], bk[j], acc0[r][j], 0,0,0);
  }
  // resid add + per-row LN statistics
  #pragma unroll
  for (int r=0;r<2;r++)
    #pragma unroll
    for (int e=0;e<4;e++){
      int row = r*16 + quad*4 + e;
      float s = 0.f, q2 = 0.f;
      #pragma unroll
      for (int j=0;j<2;j++){
        float v = acc0[r][j][e] +
                  a.resid0[rbase + (long long)(m0+row)*256 + w*32 + j*16 + l16];
        acc0[r][j][e] = v;               // x stays in registers
        s += v; q2 += v*v;
      }
      #pragma unroll
      for (int off=1; off<16; off<<=1){
        s  += __shfl_xor(s , off, 16);
        q2 += __shfl_xor(q2, off, 16);
      }
      if (l16==0){ redS[w][row] = s; redQ[w][row] = q2; }
    }
  __syncthreads();
  #pragma unroll
  for (int r=0;r<2;r++)
    #pragma unroll
    for (int e=0;e<4;e++){
      int row = r*16 + quad*4 + e;
      float tot = 0.f, tq = 0.f;
      #pragma unroll
      for (int ww=0; ww<8; ww++){ tot += redS[ww][row]; tq += redQ[ww][row]; }
      float mean = tot * (1.0f/256.0f);
      float var  = tq * (1.0f/256.0f) - mean*mean;
      float rstd = rsqrtf(var + 1e-6f);
      #pragma unroll
      for (int j=0;j<2;j++){
        int col = w*32 + j*16 + l16;
        float h = (acc0[r][j][e]-mean)*rstd*a.lnw[col] + a.lnb[col];
        int g = col >> 3;
        Hin[row*256 + ((g ^ row)*8) + (col&7)] = f2bs(h);
      }
    }
  __syncthreads();                     // Hin visible; redS region now dead

  // ------ phase A: H = relu(h@W1^T + b1) -> Hs; W1 packed frags ------------
  for (int hc=0; hc<2; ++hc){
    f32x4 acc1[2][4];
    #pragma unroll
    for (int r=0;r<2;r++)
      #pragma unroll
      for (int j=0;j<4;j++) acc1[r][j] = (f32x4){0.f,0.f,0.f,0.f};
    #pragma unroll
    for (int ks=0; ks<8; ++ks){
      short8 af[2], bk[4];
      #pragma unroll
      for (int r=0;r<2;r++){
        int rr = r*16 + l16;
        int kk = ks*4 + quad;
        af[r] = *(short8*)&Hin[rr*256 + ((kk ^ rr)*8)];
      }
      #pragma unroll
      for (int j=0;j<4;j++){
        int ht = w*8 + hc*4 + j;                  // hidden tile 0..63
        bk[j] = *(const short8*)(a.W1 + ((size_t)(ht*8 + ks)*64 + lane)*8);
      }
      #pragma unroll
      for (int r=0;r<2;r++)
        #pragma unroll
        for (int j=0;j<4;j++)
          acc1[r][j] = __builtin_amdgcn_mfma_f32_16x16x32_bf16(af[r], bk[j], acc1[r][j], 0,0,0);
    }
    #pragma unroll
    for (int r=0;r<2;r++)
      #pragma unroll
      for (int j=0;j<4;j++)
        #pragma unroll
        for (int e=0;e<4;e++){
          int row = r*16 + quad*4 + e;
          int col = w*128 + hc*64 + j*16 + l16;
          float v = fmaxf(acc1[r][j][e] + a.B1[col], 0.0f);
          int g = col>>3;
          Hs[row*1024 + ((g ^ (row&7))*8) + (col&7)] = f2bs(v);
        }
  }
  __syncthreads();                     // Hs visible to all waves

  // ------ phase B: out = H@W2^T + b2 + x; W2 packed frags ------------------
  f32x4 accB[2][2];
  #pragma unroll
  for (int r=0;r<2;r++)
    #pragma unroll
    for (int j=0;j<2;j++) accB[r][j] = (f32x4){0.f,0.f,0.f,0.f};
  #pragma unroll 8
  for (int ks=0; ks<32; ++ks){
    short8 af[2], bk[2];
    #pragma unroll
    for (int r=0;r<2;r++){
      int rr = r*16 + l16;
      int kk = ks*4 + quad;
      af[r] = *(short8*)&Hs[rr*1024 + ((kk ^ (rr&7))*8)];
    }
    #pragma unroll
    for (int j=0;j<2;j++){
      int nt = w*2 + j;                           // output-col tile 0..15
      bk[j] = *(const short8*)(a.W2 + ((size_t)(nt*32 + ks)*64 + lane)*8);
    }
    #pragma unroll
    for (int r=0;r<2;r++)
      #pragma unroll
      for (int j=0;j<2;j++)
        accB[r][j] = __builtin_amdgcn_mfma_f32_16x16x32_bf16(af[r], bk[j], accB[r][j], 0,0,0);
  }
  #pragma unroll
  for (int r=0;r<2;r++)
    #pragma unroll
    for (int j=0;j<2;j++){
      int n = w*32 + j*16 + l16;
      float bv = a.B2[n];
      #pragma unroll
      for (int e=0;e<4;e++){
        int row = r*16 + quad*4 + e;
        long long idx = obase + (long long)(m0+row)*256 + n;
        float v = accB[r][j][e] + bv + acc0[r][j][e];   // register-carried x
        a.outF[idx] = v;
        if (a.outB){
          // packed store, batch-local 512-row tiling (consumed by lnffn2)
          long long grow = (long long)(m0+row);
          long long pdst = (grow>>9)*131072
                         + (((grow&511)>>4)*8 + (n>>5))*512
                         + ((n>>3)&3)*128 + (grow&15)*8 + (n&7);
          st_out(a.outB + pdst, v);
        }
      }
    }
}

// ---------------- MFMA flash temporal causal attention ----------------
// Output o written PACKED fragment-major over global rows (for lnffn1 A).
__device__ __forceinline__ int fsw(int row){ return (row>>1)&3; }
__global__ __launch_bounds__(256) void flash_mfma(
    const bf16* __restrict__ qkv, bf16* __restrict__ o){
  int qt = (int)gridDim.x - 1 - (int)blockIdx.x;   // longest blocks first
  int h = blockIdx.y, b = blockIdx.z;
  int tid = threadIdx.x;
  int w = tid>>6, lane = tid&63, quad = lane>>4, l16 = lane&15;
  __shared__ __align__(16) bf16 Qs[64*32];
  __shared__ __align__(16) bf16 Ks[2][64*32];
  __shared__ __align__(16) bf16 Vt[2][32*72];
  __shared__ __align__(16) bf16 Ps[64*72];
  const bf16* base = qkv + (size_t)b*512*768;
  int t0 = qt*64;
  int srow = tid>>2, spos = tid&3;
  gl_lds16(base + (size_t)(t0+srow)*768 + h*32 + ((spos ^ fsw(srow))*8),
           &Qs[srow*32 + spos*8]);
  {
    const bf16* rp = base + (size_t)srow*768 + h*32;
    gl_lds16(rp + 256 + ((spos ^ fsw(srow))*8), &Ks[0][srow*32 + spos*8]);
    short8 v = *(const short8*)(rp + 512 + spos*8);
    #pragma unroll
    for (int q=0;q<8;q++){
      short tmp = v[q];
      Vt[0][(spos*8+q)*72 + srow] = *(bf16*)&tmp;
    }
  }
  f32x4 accO[2];
  accO[0] = (f32x4){0.f,0.f,0.f,0.f};
  accO[1] = (f32x4){0.f,0.f,0.f,0.f};
  float m_i[4], l_i[4];
  #pragma unroll
  for (int e=0;e<4;e++){ m_i[e] = -3.0e38f; l_i[e] = 0.0f; }
  const float scale = 0.17677669529663687f;
  __syncthreads();
  int rq = w*16 + l16;
  short8 aq = *(short8*)&Qs[rq*32 + ((quad ^ fsw(rq))*8)];

  for (int kt = 0; kt <= qt; ++kt){
    if (kt) __syncthreads();
    int cur = kt&1, nxt = cur^1;
    bool pre = (kt < qt);
    short8 vpre;
    if (pre){
      const bf16* rp = base + (size_t)((kt+1)*64 + srow)*768 + h*32;
      gl_lds16(rp + 256 + ((spos ^ fsw(srow))*8), &Ks[nxt][srow*32 + spos*8]);
      vpre = *(const short8*)(rp + 512 + spos*8);
    }
    f32x4 S[4];
    #pragma unroll
    for (int j2=0;j2<4;j2++){
      int rk = j2*16 + l16;
      short8 bk = *(short8*)&Ks[cur][rk*32 + ((quad ^ fsw(rk))*8)];
      S[j2] = __builtin_amdgcn_mfma_f32_16x16x32_bf16(aq, bk,
                (f32x4){0.f,0.f,0.f,0.f}, 0,0,0);
    }
    bool diag = (kt == qt);
    int s0 = kt*64;
    int qrow_base = t0 + w*16 + quad*4;
    #pragma unroll
    for (int e=0;e<4;e++){
      float sv[4];
      #pragma unroll
      for (int j2=0;j2<4;j2++){
        float x = S[j2][e]*scale;
        if (diag && (s0 + j2*16 + l16 > qrow_base + e)) x = -3.0e38f;
        sv[j2] = x;
      }
      float mx = fmaxf(fmaxf(sv[0],sv[1]), fmaxf(sv[2],sv[3]));
      #pragma unroll
      for (int off=1; off<16; off<<=1) mx = fmaxf(mx, __shfl_xor(mx, off, 64));
      float m_new = fmaxf(m_i[e], mx);
      float alpha = __expf(m_i[e]-m_new);
      float rs = 0.0f;
      #pragma unroll
      for (int j2=0;j2<4;j2++){
        float p = __expf(sv[j2]-m_new);
        rs += p;
        Ps[(w*16+quad*4+e)*72 + j2*16 + l16] = __float2bfloat16(p);
      }
      #pragma unroll
      for (int off=1; off<16; off<<=1) rs += __shfl_xor(rs, off, 64);
      l_i[e] = l_i[e]*alpha + rs;
      m_i[e] = m_new;
      accO[0][e] *= alpha;
      accO[1][e] *= alpha;
    }
    asm volatile("s_waitcnt lgkmcnt(0)" ::: "memory");
    __builtin_amdgcn_sched_barrier(0);
    #pragma unroll
    for (int sh=0; sh<2; ++sh){
      short8 ap = *(short8*)&Ps[(w*16+l16)*72 + sh*32 + quad*8];
      #pragma unroll
      for (int dh=0; dh<2; ++dh){
        short8 bv = *(short8*)&Vt[cur][(dh*16+l16)*72 + sh*32 + quad*8];
        accO[dh] = __builtin_amdgcn_mfma_f32_16x16x32_bf16(ap, bv, accO[dh], 0,0,0);
      }
    }
    if (pre){
      #pragma unroll
      for (int q=0;q<8;q++){
        short tmp = vpre[q];
        Vt[nxt][(spos*8+q)*72 + srow] = *(bf16*)&tmp;
      }
    }
  }
  // packed epilogue: element (r_g=b*512+t, c in {h*32+l16, h*32+16+l16})
  {
    long long fr = ((long long)b*32 + qt*4 + w)*8 + h;   // (r_g>>4)*8 + (c>>5)
    #pragma unroll
    for (int e=0;e<4;e++){
      float inv = 1.0f/l_i[e];
      long long rb8 = fr*512 + (quad*4+e)*8 + (l16&7);
      o[rb8 + (l16>>3)*128]       = __float2bfloat16(accO[0][e]*inv);
      o[rb8 + (2+(l16>>3))*128]   = __float2bfloat16(accO[1][e]*inv);
    }
  }
}

// ------- standalone fused spatial attention (full-K dbuf, 256 thr) ---------
// swB written PACKED fragment-major per batch (for lnffn2 Bm).
__global__ __launch_bounds__(256) void spatial_fused(
    const bf16* __restrict__ qk, float* __restrict__ out1,
    bf16* __restrict__ swB){
  int ct = blockIdx.x & 15, b = blockIdx.x >> 4;
  int tid = threadIdx.x;
  int w = tid>>6, lane = tid&63, quad = lane>>4, l16 = lane&15;
  __shared__ __align__(16) bf16 Qall[16*512];
  __shared__ __align__(16) bf16 Ks[2][256*64];
  __shared__ float redM[4][16], redS2[4][16];
  const bf16* qbase = qk + ((size_t)(b*256 + ct*16))*1024;
  #pragma unroll
  for (int c=0;c<4;c++){
    int ch = tid + c*256;
    int row = ch>>6, p = ch&63;
    gl_lds16(qbase + (size_t)row*1024 + ((p ^ (row&7))*8), &Qall[row*512 + p*8]);
  }
  auto stageK = [&](int h, int half){
    bf16* ks = Ks[half];
    #pragma unroll
    for (int c=0;c<8;c++){
      int ch = tid + c*256;
      int e = ch>>3, p = ch&7;
      gl_lds16(qk + ((size_t)(b*256 + e))*1024 + 512 + h*64 + ((p ^ (e&7))*8),
               &ks[e*64 + p*8]);
    }
  };
  stageK(0, 0);
  float fRes[4][4];
  #pragma unroll
  for (int j=0;j<4;j++)
    #pragma unroll
    for (int e=0;e<4;e++) fRes[j][e] = 0.0f;

  for (int h=0; h<8; ++h){
    __syncthreads();
    if (h+1 < 8) stageK(h+1, (h+1)&1);
    const bf16* kcur = Ks[h&1];
    f32x4 acc[4];
    #pragma unroll
    for (int j=0;j<4;j++) acc[j] = (f32x4){0.f,0.f,0.f,0.f};
    #pragma unroll
    for (int ki=0; ki<2; ++ki){
      int g = h*8 + ki*4 + quad;
      short8 aq = *(short8*)&Qall[l16*512 + ((g ^ (l16&7))*8)];
      #pragma unroll
      for (int j=0;j<4;j++){
        int e = w*64 + j*16 + l16;
        short8 bk = *(short8*)&kcur[e*64 + (((ki*4+quad) ^ (e&7))*8)];
        acc[j] = __builtin_amdgcn_mfma_f32_16x16x32_bf16(aq, bk, acc[j], 0,0,0);
      }
    }
    #pragma unroll
    for (int e=0;e<4;e++){
      float m = -3.0e38f;
      #pragma unroll
      for (int j=0;j<4;j++){
        float s = acc[j][e]*0.125f;
        acc[j][e] = s;
        m = fmaxf(m, s);
      }
      #pragma unroll
      for (int off=1; off<16; off<<=1) m = fmaxf(m, __shfl_xor(m, off, 16));
      if (l16==0) redM[w][quad*4+e] = m;
    }
    lgkm_barrier();
    #pragma unroll
    for (int e=0;e<4;e++){
      int r = quad*4+e;
      float m = fmaxf(fmaxf(redM[0][r],redM[1][r]), fmaxf(redM[2][r],redM[3][r]));
      float s = 0.0f;
      #pragma unroll
      for (int j=0;j<4;j++){
        float p = __expf(acc[j][e]-m);
        acc[j][e] = p; s += p;
      }
      #pragma unroll
      for (int off=1; off<16; off<<=1) s += __shfl_xor(s, off, 16);
      if (l16==0) redS2[w][r] = s;
    }
    lgkm_barrier();
    #pragma unroll
    for (int e=0;e<4;e++){
      int r = quad*4+e;
      float tot = redS2[0][r]+redS2[1][r]+redS2[2][r]+redS2[3][r];
      float inv = 0.125f/tot;
      #pragma unroll
      for (int j=0;j<4;j++) fRes[j][e] += acc[j][e]*inv;
    }
  }
  #pragma unroll
  for (int e=0;e<4;e++){
    int c = ct*16 + quad*4 + e;
    size_t rb = ((size_t)b*256 + c)*256;
    #pragma unroll
    for (int j=0;j<4;j++){
      int col = w*64 + j*16 + l16;
      out1[rb+col] = fRes[j][e];
      // packed: frag (c>>4, col>>5) of sw[b]
      size_t pdst = (size_t)b*65536
                  + ((size_t)(ct*8 + (col>>5)))*512
                  + ((col>>3)&3)*128 + (c&15)*8 + (col&7);
      swB[pdst] = __float2bfloat16(fRes[j][e]);
    }
  }
}

extern "C" void kernel_launch(void* const* d_in, const int* in_sizes, int n_in,
                              void* d_out, int out_size, void* d_ws, size_t ws_size,
                              hipStream_t stream){
  (void)in_sizes; (void)n_in; (void)out_size; (void)ws_size;
  const float* x_T  = (const float*)d_in[0];
  const float* x_S  = (const float*)d_in[1];
  const float* Wq_t = (const float*)d_in[2];
  const float* Wk_t = (const float*)d_in[3];
  const float* Wv_t = (const float*)d_in[4];
  const float* Wo   = (const float*)d_in[5];
  const float* Wq_s = (const float*)d_in[6];
  const float* Wk_s = (const float*)d_in[7];
  const float* f1w1 = (const float*)d_in[8];
  const float* f1b1 = (const float*)d_in[9];
  const float* f1w2 = (const float*)d_in[10];
  const float* f1b2 = (const float*)d_in[11];
  const float* f2w1 = (const float*)d_in[12];
  const float* f2b1 = (const float*)d_in[13];
  const float* f2w2 = (const float*)d_in[14];
  const float* f2b2 = (const float*)d_in[15];
  const float* tl1w = (const float*)d_in[16];
  const float* tl1b = (const float*)d_in[17];
  const float* tl2w = (const float*)d_in[18];
  const float* tl2b = (const float*)d_in[19];
  const float* sl1w = (const float*)d_in[20];
  const float* sl1b = (const float*)d_in[21];
  const float* flw  = (const float*)d_in[22];
  const float* flb  = (const float*)d_in[23];

  float* ws = (float*)d_ws;
  size_t off = 0;
  bf16*  Wqkvb  = (bf16*)(ws + off); off += 768*256/2;
  bf16*  Wob    = (bf16*)(ws + off); off += 256*256/2;
  bf16*  f1w1b  = (bf16*)(ws + off); off += 1024*256/2;
  bf16*  f1w2b  = (bf16*)(ws + off); off += 256*1024/2;
  bf16*  f2w1b  = (bf16*)(ws + off); off += 1024*256/2;
  bf16*  f2w2b  = (bf16*)(ws + off); off += 256*1024/2;
  bf16*  WSb    = (bf16*)(ws + off); off += 1024*512/2;
  bf16*  bufHb  = (bf16*)(ws + off); off += (size_t)8192*256/2;
  bf16*  bufHSb = (bf16*)(ws + off); off += (size_t)4096*512/2;
  bf16*  bufQKVb= (bf16*)(ws + off); off += (size_t)8192*768/2;
  bf16*  bufOb  = (bf16*)(ws + off); off += (size_t)8192*256/2;
  bf16*  bufTOb = (bf16*)(ws + off); off += (size_t)8192*256/2;
  bf16*  swB    = (bf16*)(ws + off); off += (size_t)16*256*256/2;
  bf16*  qkB    = (bf16*)(ws + off); off += (size_t)4096*1024/2;
  float* bufTO  = ws + off; off += (size_t)8192*256;

  float* out0 = (float*)d_out;                      // [B,T,C]
  float* out1 = out0 + (size_t)16*512*256;          // spatial_weights [B,C,C]

  // 1. prologue: weight prep (+frag pack for Wo/FFN weights) + LN
  ProArgs pa;
  pa.wsrc[0]=Wq_t;  pa.wdst[0]=Wqkvb;
  pa.wsrc[1]=Wk_t;  pa.wdst[1]=Wqkvb+65536;
  pa.wsrc[2]=Wv_t;  pa.wdst[2]=Wqkvb+131072;
  pa.wsrc[3]=Wo;    pa.wdst[3]=Wob;
  pa.wsrc[4]=f1w1;  pa.wdst[4]=f1w1b;
  pa.wsrc[5]=f1w2;  pa.wdst[5]=f1w2b;
  pa.wsrc[6]=f2w1;  pa.wdst[6]=f2w1b;
  pa.wsrc[7]=f2w2;  pa.wdst[7]=f2w2b;
  pa.wsrc[8]=Wq_s;  pa.wdst[8]=WSb;
  pa.wsrc[9]=Wk_s;  pa.wdst[9]=WSb+262144;
  pa.xT=x_T; pa.xS=x_S; pa.tl1w=tl1w; pa.tl1b=tl1b;
  pa.sl1w=sl1w; pa.sl1b=sl1b; pa.hT=bufHb; pa.hS=bufHSb;
  prologue<<<4864,256,0,stream>>>(pa);

  // 2. dual <128,128>: qkv (384 tiles) + spatial projection (256 tiles)
  GArgs gq, gs;
  gq.A=bufHb;  gq.B=Wqkvb; gq.outF=nullptr; gq.outB=bufQKVb;
  gq.bias=nullptr; gq.resid=nullptr;
  gq.K=256; gq.lda=256; gq.ldb=256; gq.ldc=768; gq.flags=0; gq.ty=6;
  gs.A=bufHSb; gs.B=WSb;   gs.outF=nullptr; gs.outB=qkB;
  gs.bias=nullptr; gs.resid=nullptr;
  gs.K=512; gs.lda=512; gs.ldb=512; gs.ldc=1024; gs.flags=0; gs.ty=8;
  gemm_dual<<<640,256,0,stream>>>(gq, gs, 384);

  // 3. fused spatial attention (qkB L2-hot) -> packed swB
  spatial_fused<<<256,256,0,stream>>>(qkB, out1, swB);

  // 4. temporal causal flash attention -> PACKED bf16 o
  flash_mfma<<<dim3(8,8,16),256,0,stream>>>(bufQKVb, bufOb);

  // 5. lnffn1: x = o@Wo^T + x_T ; h2 = LN(x) ; TO = relu(h2@w1^T+b1)@w2^T + b2 + x
  LnFfnArgs la1;
  la1.A=bufOb; la1.Bm=Wob;
  la1.resid0=x_T; la1.lnw=tl2w; la1.lnb=tl2b;
  la1.W1=f1w1b; la1.B1=f1b1; la1.W2=f1w2b; la1.B2=f1b2;
  la1.outF=bufTO; la1.outB=bufTOb;
  la1.sA=0; la1.sB=0; la1.sR=0; la1.sO=0;
  lnffn<<<dim3(256,1,1),512,0,stream>>>(la1);

  // 6. lnffn2: x2 = TO@sw[b]^T + TO ; h3 = LN(x2) ; out = relu(h3@w1+b1)@w2 + b2 + x2
  LnFfnArgs la2;
  la2.A=bufTOb; la2.Bm=swB;
  la2.resid0=bufTO; la2.lnw=flw; la2.lnb=flb;
  la2.W1=f2w1b; la2.B1=f2b1; la2.W2=f2w2b; la2.B2=f2b2;
  la2.outF=out0; la2.outB=nullptr;
  la2.sA=131072; la2.sB=65536; la2.sR=131072; la2.sO=131072;
  lnffn<<<dim3(16,1,16),512,0,stream>>>(la2);
}

// Round 14
// 248.019 us; speedup vs baseline: 1.3778x; 1.0271x over previous
//
#include <hip/hip_runtime.h>
#include <hip/hip_bf16.h>

typedef __hip_bfloat16 bf16;
typedef __attribute__((ext_vector_type(8))) short short8;
typedef __attribute__((ext_vector_type(4))) float f32x4;

#define F_BIAS 1
#define F_RELU 2
#define F_RES  4

__device__ __forceinline__ void st_out(float* p, float v){ *p = v; }
__device__ __forceinline__ void st_out(bf16* p, float v){ *p = __float2bfloat16(v); }
__device__ __forceinline__ short f2bs(float f){
  bf16 h = __float2bfloat16(f);
  return *reinterpret_cast<short*>(&h);
}

// async global->LDS, 16 B per lane (linear LDS dest, pre-swizzled global src).
__device__ __forceinline__ void gl_lds16(const void* g, void* l){
  __builtin_amdgcn_global_load_lds(
      (const __attribute__((address_space(1))) void*)g,
      (__attribute__((address_space(3))) void*)l, 16, 0, 0);
}

// LDS-only barrier: orders ds ops, leaves global_load_lds (vmcnt) in flight.
__device__ __forceinline__ void lgkm_barrier(){
  asm volatile("s_waitcnt lgkmcnt(0)" ::: "memory");
  __builtin_amdgcn_s_barrier();
}

// Fragment-major packed layout (weights and activations):
// fragment (tr, tk) of M[R,K] = rows tr*16..+16, k tk*32..+32, stored as 512
// contiguous shorts at ((tr*(K/32)+tk)*64 + quad*16 + l16)*8 + b, holding
// M[tr*16+l16][tk*32+quad*8+b]. A wave's fragment load = one coalesced 1KB.

// ------------- prologue: weight prep (+fragment pack) + LN(x_T/x_S) --------
struct ProArgs {
  const float* wsrc[10];
  bf16* wdst[10];
  const float *xT, *xS, *tl1w, *tl1b, *sl1w, *sl1b;
  bf16 *hT, *hS;
};

template<int RL>
__device__ __forceinline__ void wave_ln(bf16* __restrict__ dst,
    const float* __restrict__ src, const float* __restrict__ w,
    const float* __restrict__ bvec, int row){
  int lane = threadIdx.x & 63;
  const float* s = src + (size_t)row*RL;
  float4 v0 = *(const float4*)(s + lane*4);
  float4 v1 = {0.f,0.f,0.f,0.f};
  float sum = v0.x+v0.y+v0.z+v0.w;
  float sq  = v0.x*v0.x+v0.y*v0.y+v0.z*v0.z+v0.w*v0.w;
  if (RL == 512){
    v1 = *(const float4*)(s + 256 + lane*4);
    sum += v1.x+v1.y+v1.z+v1.w;
    sq  += v1.x*v1.x+v1.y*v1.y+v1.z*v1.z+v1.w*v1.w;
  }
  #pragma unroll
  for (int off=32; off; off>>=1){
    sum += __shfl_xor(sum, off, 64);
    sq  += __shfl_xor(sq , off, 64);
  }
  const float inv = 1.0f/(float)RL;
  float mean = sum*inv;
  float rstd = rsqrtf(sq*inv - mean*mean + 1e-6f);
  float4 w0 = *(const float4*)(w + lane*4);
  float4 b0 = *(const float4*)(bvec + lane*4);
  bf16* d = dst + (size_t)row*RL;
  short4 o;
  o.x = f2bs((v0.x-mean)*rstd*w0.x + b0.x);
  o.y = f2bs((v0.y-mean)*rstd*w0.y + b0.y);
  o.z = f2bs((v0.z-mean)*rstd*w0.z + b0.z);
  o.w = f2bs((v0.w-mean)*rstd*w0.w + b0.w);
  *(short4*)((short*)d + lane*4) = o;
  if (RL == 512){
    float4 w1 = *(const float4*)(w + 256 + lane*4);
    float4 b1 = *(const float4*)(bvec + 256 + lane*4);
    short4 o1;
    o1.x = f2bs((v1.x-mean)*rstd*w1.x + b1.x);
    o1.y = f2bs((v1.y-mean)*rstd*w1.y + b1.y);
    o1.z = f2bs((v1.z-mean)*rstd*w1.z + b1.z);
    o1.w = f2bs((v1.w-mean)*rstd*w1.w + b1.w);
    *(short4*)((short*)d + 256 + lane*4) = o1;
  }
}

__global__ __launch_bounds__(256) void prologue(ProArgs a){
  int blk = blockIdx.x;
  int wid = threadIdx.x >> 6;
  if (blk < 1792){
    int v = blk*256 + threadIdx.x;
    int e = v*4;
    int seg = (e>=65536)+(e>=131072)+(e>=196608)+(e>=262144)+(e>=524288)
            + (e>=786432)+(e>=1048576)+(e>=1310720)+(e>=1572864);
    const int starts[10] = {0,65536,131072,196608,262144,524288,786432,
                            1048576,1310720,1572864};
    int off = e - starts[seg];
    float4 f = *(const float4*)(a.wsrc[seg] + off);
    short4 o;
    o.x = f2bs(f.x); o.y = f2bs(f.y); o.z = f2bs(f.z); o.w = f2bs(f.w);
    if (seg >= 3 && seg <= 7){
      // fragment-major pack; ld = K of the matrix (256 or 1024)
      int ldlog = (seg==5 || seg==7) ? 10 : 8;
      int r  = off >> ldlog;
      int c  = off & ((1<<ldlog)-1);
      int tn = r >> 4, lr = r & 15;
      int tk = c >> 5, qd = (c>>3)&3, b = c&7;
      int nkt = 1 << (ldlog-5);
      int dst = (((tn*nkt + tk)*64) + qd*16 + lr)*8 + b;
      *(short4*)((short*)a.wdst[seg] + dst) = o;
    } else {
      *(short4*)((short*)a.wdst[seg] + off) = o;
    }
  } else if (blk < 1792 + 2048){
    wave_ln<256>(a.hT, a.xT, a.tl1w, a.tl1b, (blk-1792)*4 + wid);
  } else {
    wave_ln<512>(a.hS, a.xS, a.sl1w, a.sl1b, (blk-3840)*4 + wid);
  }
}

// -- MFMA bf16 GEMM body (256 thr): dbuf, barrier at TOP ---------------------
template<int BM, int BN, int BK>
__device__ __forceinline__ void gemm_body(
    short* __restrict__ AsB, short* __restrict__ BsB,
    const bf16* __restrict__ A, const bf16* __restrict__ B,
    float* __restrict__ outF, bf16* __restrict__ outB,
    const float* __restrict__ bias, const float* __restrict__ resid,
    int K, int lda, int ldb, int ldc, int flags, int m0, int n0){
  int tid = threadIdx.x;
  int w = tid>>6, lane = tid&63, quad = lane>>4, l16 = lane&15;
  constexpr int MF  = BM/32;
  constexpr int NF  = BN/32;
  constexpr int CPR = BK/8;
  constexpr int CA  = BM*CPR/256;
  constexpr int CB  = BN*CPR/256;
  int wm = (w>>1)*(BM/2), wn = (w&1)*(BN/2);
  f32x4 acc[MF][NF];
  #pragma unroll
  for (int r=0;r<MF;r++)
    #pragma unroll
    for (int j=0;j<NF;j++)
      acc[r][j] = (f32x4){0.f,0.f,0.f,0.f};

  auto stage = [&](int k0, int half){
    short* as = AsB + half*(BM*BK);
    short* bs = BsB + half*(BN*BK);
    #pragma unroll
    for (int c=0;c<CA;c++){
      int ch = tid + c*256;
      int row = ch / CPR, p = ch % CPR;
      gl_lds16(A + (size_t)(m0+row)*lda + k0 + ((p ^ (row&(CPR-1)))*8),
               &as[row*BK + p*8]);
    }
    #pragma unroll
    for (int c=0;c<CB;c++){
      int ch = tid + c*256;
      int row = ch / CPR, p = ch % CPR;
      gl_lds16(B + (size_t)(n0+row)*ldb + k0 + ((p ^ (row&(CPR-1)))*8),
               &bs[row*BK + p*8]);
    }
  };

  stage(0, 0);
  int nk = K / BK;
  for (int t = 0; t < nk; ++t){
    __syncthreads();
    if (t+1 < nk) stage((t+1)*BK, (t+1)&1);
    const short* as = AsB + (t&1)*(BM*BK);
    const short* bs = BsB + (t&1)*(BN*BK);
    #pragma unroll
    for (int ks=0; ks<BK/32; ++ks){
      short8 af[MF], bfr[NF];
      #pragma unroll
      for (int r=0;r<MF;r++){
        int rr = wm + r*16 + l16;
        af[r] = *(short8*)&as[rr*BK + (((ks*4+quad) ^ (rr&(CPR-1)))*8)];
      }
      #pragma unroll
      for (int j=0;j<NF;j++){
        int rr = wn + j*16 + l16;
        bfr[j] = *(short8*)&bs[rr*BK + (((ks*4+quad) ^ (rr&(CPR-1)))*8)];
      }
      #pragma unroll
      for (int r=0;r<MF;r++)
        #pragma unroll
        for (int j=0;j<NF;j++)
          acc[r][j] = __builtin_amdgcn_mfma_f32_16x16x32_bf16(af[r], bfr[j], acc[r][j], 0,0,0);
    }
  }
  #pragma unroll
  for (int r=0;r<MF;r++){
    int mb = m0 + wm + r*16 + quad*4;
    #pragma unroll
    for (int j=0;j<NF;j++){
      int n = n0 + wn + j*16 + l16;
      float bv = (flags & F_BIAS) ? bias[n] : 0.0f;
      #pragma unroll
      for (int e=0;e<4;e++){
        float v = acc[r][j][e] + bv;
        if (flags & F_RELU) v = fmaxf(v, 0.0f);
        long long idx = (long long)(mb+e)*ldc + n;
        if (flags & F_RES) v += resid[idx];
        if (outF) outF[idx] = v;
        if (outB) st_out(outB + idx, v);
      }
    }
  }
}

// ---- dual GEMM: two independent <128,128> GEMMs in one launch (1-D grid) ---
struct GArgs {
  const bf16 *A, *B;
  float* outF; bf16* outB;
  const float *bias, *resid;
  int K, lda, ldb, ldc, flags, ty;
};
__global__ __launch_bounds__(256) void gemm_dual(GArgs g0, GArgs g1, int n0){
  __shared__ __align__(16) short As[2*128*64];
  __shared__ __align__(16) short Bs[2*128*64];
  int id = blockIdx.x;
  bool first = id < n0;
  const GArgs& g = first ? g0 : g1;
  int t = first ? id : id - n0;
  int bx = t / g.ty, by = t - bx*g.ty;
  gemm_body<128,128,64>(As, Bs, g.A, g.B, g.outF, g.outB, g.bias, g.resid,
                        g.K, g.lda, g.ldb, g.ldc, g.flags, bx*128, by*128);
}

// ---- lnffn2x: BOTH transformer tails fused, TO never touches HBM ----------
// x  = o@Wo^T + x_T ; h2 = LN(x) ; TO = relu(h2@W1a+b1a)@W2a + b2a + x
// x2 = TO@sw[b]^T + TO ; h3 = LN(x2) ; out = relu(h3@W1b+b1b)@W2b + b2b + x2
// All global MFMA operands packed fragment-major; x/TO/x2 register-carried.
struct L2XArgs {
  const bf16 *A;              // bufOb packed (o)
  const bf16 *Wo;             // packed [256,256]
  const float *xT;            // row-major f32 resid
  const float *ln1w, *ln1b;
  const bf16 *W1a; const float *B1a;
  const bf16 *W2a; const float *B2a;
  const bf16 *sw;             // packed, +b*65536 per batch
  const float *ln2w, *ln2b;
  const bf16 *W1b; const float *B1b;
  const bf16 *W2b; const float *B2b;
  float *out0;                // row-major f32
};

// FFN block over Hin (h, XOR g^row) -> outv = relu(h@W1+b1)@W2 + b2 + resid.
// Caller must have Hin visible (barrier) before calling; leaves Hs dirty.
__device__ __forceinline__ void ffn_block(
    short* Hin, short* Hs,
    const bf16* W1, const float* B1, const bf16* W2, const float* B2,
    int w, int quad, int l16, int lane,
    f32x4 resid[2][2], f32x4 outv[2][2]){
  // phase A: H = relu(h@W1^T + b1) -> Hs
  for (int hc=0; hc<2; ++hc){
    f32x4 acc1[2][4];
    #pragma unroll
    for (int r=0;r<2;r++)
      #pragma unroll
      for (int j=0;j<4;j++) acc1[r][j] = (f32x4){0.f,0.f,0.f,0.f};
    #pragma unroll
    for (int ks=0; ks<8; ++ks){
      short8 af[2], bk[4];
      #pragma unroll
      for (int r=0;r<2;r++){
        int rr = r*16 + l16;
        int kk = ks*4 + quad;
        af[r] = *(short8*)&Hin[rr*256 + ((kk ^ rr)*8)];
      }
      #pragma unroll
      for (int j=0;j<4;j++){
        int ht = w*8 + hc*4 + j;
        bk[j] = *(const short8*)(W1 + ((size_t)(ht*8 + ks)*64 + lane)*8);
      }
      #pragma unroll
      for (int r=0;r<2;r++)
        #pragma unroll
        for (int j=0;j<4;j++)
          acc1[r][j] = __builtin_amdgcn_mfma_f32_16x16x32_bf16(af[r], bk[j], acc1[r][j], 0,0,0);
    }
    #pragma unroll
    for (int r=0;r<2;r++)
      #pragma unroll
      for (int j=0;j<4;j++)
        #pragma unroll
        for (int e=0;e<4;e++){
          int row = r*16 + quad*4 + e;
          int col = w*128 + hc*64 + j*16 + l16;
          float v = fmaxf(acc1[r][j][e] + B1[col], 0.0f);
          int g = col>>3;
          Hs[row*1024 + ((g ^ (row&7))*8) + (col&7)] = f2bs(v);
        }
  }
  __syncthreads();                     // Hs visible
  // phase B: out = H@W2^T + b2 + resid
  f32x4 accB[2][2];
  #pragma unroll
  for (int r=0;r<2;r++)
    #pragma unroll
    for (int j=0;j<2;j++) accB[r][j] = (f32x4){0.f,0.f,0.f,0.f};
  #pragma unroll 8
  for (int ks=0; ks<32; ++ks){
    short8 af[2], bk[2];
    #pragma unroll
    for (int r=0;r<2;r++){
      int rr = r*16 + l16;
      int kk = ks*4 + quad;
      af[r] = *(short8*)&Hs[rr*1024 + ((kk ^ (rr&7))*8)];
    }
    #pragma unroll
    for (int j=0;j<2;j++){
      int nt = w*2 + j;
      bk[j] = *(const short8*)(W2 + ((size_t)(nt*32 + ks)*64 + lane)*8);
    }
    #pragma unroll
    for (int r=0;r<2;r++)
      #pragma unroll
      for (int j=0;j<2;j++)
        accB[r][j] = __builtin_amdgcn_mfma_f32_16x16x32_bf16(af[r], bk[j], accB[r][j], 0,0,0);
  }
  #pragma unroll
  for (int r=0;r<2;r++)
    #pragma unroll
    for (int j=0;j<2;j++){
      int n = w*32 + j*16 + l16;
      float bv = B2[n];
      #pragma unroll
      for (int e=0;e<4;e++)
        outv[r][j][e] = accB[r][j][e] + bv + resid[r][j][e];
    }
}

__global__ __launch_bounds__(512) void lnffn2x(L2XArgs a){
  __shared__ __align__(16) short Hin[32*256];    // 16 KB (XOR g^row)
  __shared__ __align__(16) short Hs[32*1024];    // 64 KB (XOR g^(row&7))
  float (*redS)[32] = (float(*)[32])Hs;          // overlay (Hs dead at use)
  float (*redQ)[32] = (float(*)[32])(Hs + 512);
  int tid = threadIdx.x;
  int w = tid>>6, lane = tid&63, quad = lane>>4, l16 = lane&15;
  int m0 = blockIdx.x*32;
  int mt0 = m0 >> 4;
  int bz = blockIdx.x >> 4;            // batch (512 rows per batch)
  const bf16* swb = a.sw + (size_t)bz*65536;

  // helper: LN over reg tile -> Hin (XOR g^row layout)
  auto ln_to_hin = [&](f32x4 x[2][2], const float* lw, const float* lb){
    #pragma unroll
    for (int r=0;r<2;r++)
      #pragma unroll
      for (int e=0;e<4;e++){
        int row = r*16 + quad*4 + e;
        float s = 0.f, q2 = 0.f;
        #pragma unroll
        for (int j=0;j<2;j++){ s += x[r][j][e]; q2 += x[r][j][e]*x[r][j][e]; }
        #pragma unroll
        for (int off=1; off<16; off<<=1){
          s  += __shfl_xor(s , off, 16);
          q2 += __shfl_xor(q2, off, 16);
        }
        if (l16==0){ redS[w][row] = s; redQ[w][row] = q2; }
      }
    __syncthreads();
    #pragma unroll
    for (int r=0;r<2;r++)
      #pragma unroll
      for (int e=0;e<4;e++){
        int row = r*16 + quad*4 + e;
        float tot = 0.f, tq = 0.f;
        #pragma unroll
        for (int ww=0; ww<8; ww++){ tot += redS[ww][row]; tq += redQ[ww][row]; }
        float mean = tot * (1.0f/256.0f);
        float var  = tq * (1.0f/256.0f) - mean*mean;
        float rstd = rsqrtf(var + 1e-6f);
        #pragma unroll
        for (int j=0;j<2;j++){
          int col = w*32 + j*16 + l16;
          float h = (x[r][j][e]-mean)*rstd*lw[col] + lb[col];
          int g = col >> 3;
          Hin[row*256 + ((g ^ row)*8) + (col&7)] = f2bs(h);
        }
      }
    __syncthreads();                   // Hin visible
  };

  // ---- phase 0: x = o@Wo^T + x_T (packed A and B fragments) ----
  f32x4 accX[2][2];
  #pragma unroll
  for (int r=0;r<2;r++)
    #pragma unroll
    for (int j=0;j<2;j++) accX[r][j] = (f32x4){0.f,0.f,0.f,0.f};
  #pragma unroll
  for (int ks=0; ks<8; ++ks){
    short8 af[2], bk[2];
    #pragma unroll
    for (int r=0;r<2;r++)
      af[r] = *(const short8*)(a.A + (((size_t)(mt0+r)*8 + ks)*64 + lane)*8);
    #pragma unroll
    for (int j=0;j<2;j++){
      int tile = w*2 + j;
      bk[j] = *(const short8*)(a.Wo + ((size_t)(tile*8 + ks)*64 + lane)*8);
    }
    #pragma unroll
    for (int r=0;r<2;r++)
      #pragma unroll
      for (int j=0;j<2;j++)
        accX[r][j] = __builtin_amdgcn_mfma_f32_16x16x32_bf16(af[r], bk[j], accX[r][j], 0,0,0);
  }
  #pragma unroll
  for (int r=0;r<2;r++)
    #pragma unroll
    for (int e=0;e<4;e++){
      int row = r*16 + quad*4 + e;
      #pragma unroll
      for (int j=0;j<2;j++)
        accX[r][j][e] += a.xT[(long long)(m0+row)*256 + w*32 + j*16 + l16];
    }
  ln_to_hin(accX, a.ln1w, a.ln1b);     // h2 -> Hin

  // ---- FFN1: TO = relu(h2@W1a+b1a)@W2a + b2a + x (registers) ----
  f32x4 accT[2][2];
  ffn_block(Hin, Hs, a.W1a, a.B1a, a.W2a, a.B2a, w, quad, l16, lane, accX, accT);

  // ---- TO -> Hin (bf16, XOR layout) for phase 0b A-fragments ----
  // (all FFN1 Hs reads and earlier Hin reads complete before this barrier)
  #pragma unroll
  for (int r=0;r<2;r++)
    #pragma unroll
    for (int j=0;j<2;j++)
      #pragma unroll
      for (int e=0;e<4;e++){
        int row = r*16 + quad*4 + e;
        int col = w*32 + j*16 + l16;
        int g = col >> 3;
        Hin[row*256 + ((g ^ row)*8) + (col&7)] = f2bs(accT[r][j][e]);
      }
  __syncthreads();

  // ---- phase 0b: x2 = TO@sw^T + TO (A from LDS, B packed global) ----
  f32x4 accX2[2][2];
  #pragma unroll
  for (int r=0;r<2;r++)
    #pragma unroll
    for (int j=0;j<2;j++) accX2[r][j] = (f32x4){0.f,0.f,0.f,0.f};
  #pragma unroll
  for (int ks=0; ks<8; ++ks){
    short8 af[2], bk[2];
    #pragma unroll
    for (int r=0;r<2;r++){
      int rr = r*16 + l16;
      int kk = ks*4 + quad;
      af[r] = *(short8*)&Hin[rr*256 + ((kk ^ rr)*8)];
    }
    #pragma unroll
    for (int j=0;j<2;j++){
      int tile = w*2 + j;
      bk[j] = *(const short8*)(swb + ((size_t)(tile*8 + ks)*64 + lane)*8);
    }
    #pragma unroll
    for (int r=0;r<2;r++)
      #pragma unroll
      for (int j=0;j<2;j++)
        accX2[r][j] = __builtin_amdgcn_mfma_f32_16x16x32_bf16(af[r], bk[j], accX2[r][j], 0,0,0);
  }
  #pragma unroll
  for (int r=0;r<2;r++)
    #pragma unroll
    for (int j=0;j<2;j++)
      #pragma unroll
      for (int e=0;e<4;e++)
        accX2[r][j][e] += accT[r][j][e];   // + TO (register-carried)
  ln_to_hin(accX2, a.ln2w, a.ln2b);    // h3 -> Hin (reads done pre-barrier)

  // ---- FFN2: out = relu(h3@W1b+b1b)@W2b + b2b + x2 ----
  f32x4 accO[2][2];
  ffn_block(Hin, Hs, a.W1b, a.B1b, a.W2b, a.B2b, w, quad, l16, lane, accX2, accO);

  #pragma unroll
  for (int r=0;r<2;r++)
    #pragma unroll
    for (int j=0;j<2;j++){
      int n = w*32 + j*16 + l16;
      #pragma unroll
      for (int e=0;e<4;e++){
        int row = r*16 + quad*4 + e;
        a.out0[(long long)(m0+row)*256 + n] = accO[r][j][e];
      }
    }
}

// ---------------- MFMA flash temporal causal attention ----------------
// Output o written PACKED fragment-major over global rows (for lnffn2x A).
__device__ __forceinline__ int fsw(int row){ return (row>>1)&3; }
__global__ __launch_bounds__(256) void flash_mfma(
    const bf16* __restrict__ qkv, bf16* __restrict__ o){
  int qt = (int)gridDim.x - 1 - (int)blockIdx.x;   // longest blocks first
  int h = blockIdx.y, b = blockIdx.z;
  int tid = threadIdx.x;
  int w = tid>>6, lane = tid&63, quad = lane>>4, l16 = lane&15;
  __shared__ __align__(16) bf16 Qs[64*32];
  __shared__ __align__(16) bf16 Ks[2][64*32];
  __shared__ __align__(16) bf16 Vt[2][32*72];
  __shared__ __align__(16) bf16 Ps[64*72];
  const bf16* base = qkv + (size_t)b*512*768;
  int t0 = qt*64;
  int srow = tid>>2, spos = tid&3;
  gl_lds16(base + (size_t)(t0+srow)*768 + h*32 + ((spos ^ fsw(srow))*8),
           &Qs[srow*32 + spos*8]);
  {
    const bf16* rp = base + (size_t)srow*768 + h*32;
    gl_lds16(rp + 256 + ((spos ^ fsw(srow))*8), &Ks[0][srow*32 + spos*8]);
    short8 v = *(const short8*)(rp + 512 + spos*8);
    #pragma unroll
    for (int q=0;q<8;q++){
      short tmp = v[q];
      Vt[0][(spos*8+q)*72 + srow] = *(bf16*)&tmp;
    }
  }
  f32x4 accO[2];
  accO[0] = (f32x4){0.f,0.f,0.f,0.f};
  accO[1] = (f32x4){0.f,0.f,0.f,0.f};
  float m_i[4], l_i[4];
  #pragma unroll
  for (int e=0;e<4;e++){ m_i[e] = -3.0e38f; l_i[e] = 0.0f; }
  const float scale = 0.17677669529663687f;
  __syncthreads();
  int rq = w*16 + l16;
  short8 aq = *(short8*)&Qs[rq*32 + ((quad ^ fsw(rq))*8)];

  for (int kt = 0; kt <= qt; ++kt){
    if (kt) __syncthreads();
    int cur = kt&1, nxt = cur^1;
    bool pre = (kt < qt);
    short8 vpre;
    if (pre){
      const bf16* rp = base + (size_t)((kt+1)*64 + srow)*768 + h*32;
      gl_lds16(rp + 256 + ((spos ^ fsw(srow))*8), &Ks[nxt][srow*32 + spos*8]);
      vpre = *(const short8*)(rp + 512 + spos*8);
    }
    f32x4 S[4];
    #pragma unroll
    for (int j2=0;j2<4;j2++){
      int rk = j2*16 + l16;
      short8 bk = *(short8*)&Ks[cur][rk*32 + ((quad ^ fsw(rk))*8)];
      S[j2] = __builtin_amdgcn_mfma_f32_16x16x32_bf16(aq, bk,
                (f32x4){0.f,0.f,0.f,0.f}, 0,0,0);
    }
    bool diag = (kt == qt);
    int s0 = kt*64;
    int qrow_base = t0 + w*16 + quad*4;
    #pragma unroll
    for (int e=0;e<4;e++){
      float sv[4];
      #pragma unroll
      for (int j2=0;j2<4;j2++){
        float x = S[j2][e]*scale;
        if (diag && (s0 + j2*16 + l16 > qrow_base + e)) x = -3.0e38f;
        sv[j2] = x;
      }
      float mx = fmaxf(fmaxf(sv[0],sv[1]), fmaxf(sv[2],sv[3]));
      #pragma unroll
      for (int off=1; off<16; off<<=1) mx = fmaxf(mx, __shfl_xor(mx, off, 64));
      float m_new = fmaxf(m_i[e], mx);
      float alpha = __expf(m_i[e]-m_new);
      float rs = 0.0f;
      #pragma unroll
      for (int j2=0;j2<4;j2++){
        float p = __expf(sv[j2]-m_new);
        rs += p;
        Ps[(w*16+quad*4+e)*72 + j2*16 + l16] = __float2bfloat16(p);
      }
      #pragma unroll
      for (int off=1; off<16; off<<=1) rs += __shfl_xor(rs, off, 64);
      l_i[e] = l_i[e]*alpha + rs;
      m_i[e] = m_new;
      accO[0][e] *= alpha;
      accO[1][e] *= alpha;
    }
    asm volatile("s_waitcnt lgkmcnt(0)" ::: "memory");
    __builtin_amdgcn_sched_barrier(0);
    #pragma unroll
    for (int sh=0; sh<2; ++sh){
      short8 ap = *(short8*)&Ps[(w*16+l16)*72 + sh*32 + quad*8];
      #pragma unroll
      for (int dh=0; dh<2; ++dh){
        short8 bv = *(short8*)&Vt[cur][(dh*16+l16)*72 + sh*32 + quad*8];
        accO[dh] = __builtin_amdgcn_mfma_f32_16x16x32_bf16(ap, bv, accO[dh], 0,0,0);
      }
    }
    if (pre){
      #pragma unroll
      for (int q=0;q<8;q++){
        short tmp = vpre[q];
        Vt[nxt][(spos*8+q)*72 + srow] = *(bf16*)&tmp;
      }
    }
  }
  // packed epilogue: element (r_g=b*512+t, c in {h*32+l16, h*32+16+l16})
  {
    long long fr = ((long long)b*32 + qt*4 + w)*8 + h;   // (r_g>>4)*8 + (c>>5)
    #pragma unroll
    for (int e=0;e<4;e++){
      float inv = 1.0f/l_i[e];
      long long rb8 = fr*512 + (quad*4+e)*8 + (l16&7);
      o[rb8 + (l16>>3)*128]       = __float2bfloat16(accO[0][e]*inv);
      o[rb8 + (2+(l16>>3))*128]   = __float2bfloat16(accO[1][e]*inv);
    }
  }
}

// ------- standalone fused spatial attention (full-K dbuf, 256 thr) ---------
// swB written PACKED fragment-major per batch (for lnffn2x phase 0b).
__global__ __launch_bounds__(256) void spatial_fused(
    const bf16* __restrict__ qk, float* __restrict__ out1,
    bf16* __restrict__ swB){
  int ct = blockIdx.x & 15, b = blockIdx.x >> 4;
  int tid = threadIdx.x;
  int w = tid>>6, lane = tid&63, quad = lane>>4, l16 = lane&15;
  __shared__ __align__(16) bf16 Qall[16*512];
  __shared__ __align__(16) bf16 Ks[2][256*64];
  __shared__ float redM[4][16], redS2[4][16];
  const bf16* qbase = qk + ((size_t)(b*256 + ct*16))*1024;
  #pragma unroll
  for (int c=0;c<4;c++){
    int ch = tid + c*256;
    int row = ch>>6, p = ch&63;
    gl_lds16(qbase + (size_t)row*1024 + ((p ^ (row&7))*8), &Qall[row*512 + p*8]);
  }
  auto stageK = [&](int h, int half){
    bf16* ks = Ks[half];
    #pragma unroll
    for (int c=0;c<8;c++){
      int ch = tid + c*256;
      int e = ch>>3, p = ch&7;
      gl_lds16(qk + ((size_t)(b*256 + e))*1024 + 512 + h*64 + ((p ^ (e&7))*8),
               &ks[e*64 + p*8]);
    }
  };
  stageK(0, 0);
  float fRes[4][4];
  #pragma unroll
  for (int j=0;j<4;j++)
    #pragma unroll
    for (int e=0;e<4;e++) fRes[j][e] = 0.0f;

  for (int h=0; h<8; ++h){
    __syncthreads();
    if (h+1 < 8) stageK(h+1, (h+1)&1);
    const bf16* kcur = Ks[h&1];
    f32x4 acc[4];
    #pragma unroll
    for (int j=0;j<4;j++) acc[j] = (f32x4){0.f,0.f,0.f,0.f};
    #pragma unroll
    for (int ki=0; ki<2; ++ki){
      int g = h*8 + ki*4 + quad;
      short8 aq = *(short8*)&Qall[l16*512 + ((g ^ (l16&7))*8)];
      #pragma unroll
      for (int j=0;j<4;j++){
        int e = w*64 + j*16 + l16;
        short8 bk = *(short8*)&kcur[e*64 + (((ki*4+quad) ^ (e&7))*8)];
        acc[j] = __builtin_amdgcn_mfma_f32_16x16x32_bf16(aq, bk, acc[j], 0,0,0);
      }
    }
    #pragma unroll
    for (int e=0;e<4;e++){
      float m = -3.0e38f;
      #pragma unroll
      for (int j=0;j<4;j++){
        float s = acc[j][e]*0.125f;
        acc[j][e] = s;
        m = fmaxf(m, s);
      }
      #pragma unroll
      for (int off=1; off<16; off<<=1) m = fmaxf(m, __shfl_xor(m, off, 16));
      if (l16==0) redM[w][quad*4+e] = m;
    }
    lgkm_barrier();
    #pragma unroll
    for (int e=0;e<4;e++){
      int r = quad*4+e;
      float m = fmaxf(fmaxf(redM[0][r],redM[1][r]), fmaxf(redM[2][r],redM[3][r]));
      float s = 0.0f;
      #pragma unroll
      for (int j=0;j<4;j++){
        float p = __expf(acc[j][e]-m);
        acc[j][e] = p; s += p;
      }
      #pragma unroll
      for (int off=1; off<16; off<<=1) s += __shfl_xor(s, off, 16);
      if (l16==0) redS2[w][r] = s;
    }
    lgkm_barrier();
    #pragma unroll
    for (int e=0;e<4;e++){
      int r = quad*4+e;
      float tot = redS2[0][r]+redS2[1][r]+redS2[2][r]+redS2[3][r];
      float inv = 0.125f/tot;
      #pragma unroll
      for (int j=0;j<4;j++) fRes[j][e] += acc[j][e]*inv;
    }
  }
  #pragma unroll
  for (int e=0;e<4;e++){
    int c = ct*16 + quad*4 + e;
    size_t rb = ((size_t)b*256 + c)*256;
    #pragma unroll
    for (int j=0;j<4;j++){
      int col = w*64 + j*16 + l16;
      out1[rb+col] = fRes[j][e];
      // packed: frag (c>>4, col>>5) of sw[b]
      size_t pdst = (size_t)b*65536
                  + ((size_t)(ct*8 + (col>>5)))*512
                  + ((col>>3)&3)*128 + (c&15)*8 + (col&7);
      swB[pdst] = __float2bfloat16(fRes[j][e]);
    }
  }
}

extern "C" void kernel_launch(void* const* d_in, const int* in_sizes, int n_in,
                              void* d_out, int out_size, void* d_ws, size_t ws_size,
                              hipStream_t stream){
  (void)in_sizes; (void)n_in; (void)out_size; (void)ws_size;
  const float* x_T  = (const float*)d_in[0];
  const float* x_S  = (const float*)d_in[1];
  const float* Wq_t = (const float*)d_in[2];
  const float* Wk_t = (const float*)d_in[3];
  const float* Wv_t = (const float*)d_in[4];
  const float* Wo   = (const float*)d_in[5];
  const float* Wq_s = (const float*)d_in[6];
  const float* Wk_s = (const float*)d_in[7];
  const float* f1w1 = (const float*)d_in[8];
  const float* f1b1 = (const float*)d_in[9];
  const float* f1w2 = (const float*)d_in[10];
  const float* f1b2 = (const float*)d_in[11];
  const float* f2w1 = (const float*)d_in[12];
  const float* f2b1 = (const float*)d_in[13];
  const float* f2w2 = (const float*)d_in[14];
  const float* f2b2 = (const float*)d_in[15];
  const float* tl1w = (const float*)d_in[16];
  const float* tl1b = (const float*)d_in[17];
  const float* tl2w = (const float*)d_in[18];
  const float* tl2b = (const float*)d_in[19];
  const float* sl1w = (const float*)d_in[20];
  const float* sl1b = (const float*)d_in[21];
  const float* flw  = (const float*)d_in[22];
  const float* flb  = (const float*)d_in[23];

  float* ws = (float*)d_ws;
  size_t off = 0;
  bf16*  Wqkvb  = (bf16*)(ws + off); off += 768*256/2;
  bf16*  Wob    = (bf16*)(ws + off); off += 256*256/2;
  bf16*  f1w1b  = (bf16*)(ws + off); off += 1024*256/2;
  bf16*  f1w2b  = (bf16*)(ws + off); off += 256*1024/2;
  bf16*  f2w1b  = (bf16*)(ws + off); off += 1024*256/2;
  bf16*  f2w2b  = (bf16*)(ws + off); off += 256*1024/2;
  bf16*  WSb    = (bf16*)(ws + off); off += 1024*512/2;
  bf16*  bufHb  = (bf16*)(ws + off); off += (size_t)8192*256/2;
  bf16*  bufHSb = (bf16*)(ws + off); off += (size_t)4096*512/2;
  bf16*  bufQKVb= (bf16*)(ws + off); off += (size_t)8192*768/2;
  bf16*  bufOb  = (bf16*)(ws + off); off += (size_t)8192*256/2;
  bf16*  swB    = (bf16*)(ws + off); off += (size_t)16*256*256/2;
  bf16*  qkB    = (bf16*)(ws + off); off += (size_t)4096*1024/2;

  float* out0 = (float*)d_out;                      // [B,T,C]
  float* out1 = out0 + (size_t)16*512*256;          // spatial_weights [B,C,C]

  // 1. prologue: weight prep (+frag pack for Wo/FFN weights) + LN
  ProArgs pa;
  pa.wsrc[0]=Wq_t;  pa.wdst[0]=Wqkvb;
  pa.wsrc[1]=Wk_t;  pa.wdst[1]=Wqkvb+65536;
  pa.wsrc[2]=Wv_t;  pa.wdst[2]=Wqkvb+131072;
  pa.wsrc[3]=Wo;    pa.wdst[3]=Wob;
  pa.wsrc[4]=f1w1;  pa.wdst[4]=f1w1b;
  pa.wsrc[5]=f1w2;  pa.wdst[5]=f1w2b;
  pa.wsrc[6]=f2w1;  pa.wdst[6]=f2w1b;
  pa.wsrc[7]=f2w2;  pa.wdst[7]=f2w2b;
  pa.wsrc[8]=Wq_s;  pa.wdst[8]=WSb;
  pa.wsrc[9]=Wk_s;  pa.wdst[9]=WSb+262144;
  pa.xT=x_T; pa.xS=x_S; pa.tl1w=tl1w; pa.tl1b=tl1b;
  pa.sl1w=sl1w; pa.sl1b=sl1b; pa.hT=bufHb; pa.hS=bufHSb;
  prologue<<<4864,256,0,stream>>>(pa);

  // 2. dual <128,128>: qkv (384 tiles) + spatial projection (256 tiles)
  GArgs gq, gs;
  gq.A=bufHb;  gq.B=Wqkvb; gq.outF=nullptr; gq.outB=bufQKVb;
  gq.bias=nullptr; gq.resid=nullptr;
  gq.K=256; gq.lda=256; gq.ldb=256; gq.ldc=768; gq.flags=0; gq.ty=6;
  gs.A=bufHSb; gs.B=WSb;   gs.outF=nullptr; gs.outB=qkB;
  gs.bias=nullptr; gs.resid=nullptr;
  gs.K=512; gs.lda=512; gs.ldb=512; gs.ldc=1024; gs.flags=0; gs.ty=8;
  gemm_dual<<<640,256,0,stream>>>(gq, gs, 384);

  // 3. fused spatial attention (qkB L2-hot) -> packed swB
  spatial_fused<<<256,256,0,stream>>>(qkB, out1, swB);

  // 4. temporal causal flash attention -> PACKED bf16 o
  flash_mfma<<<dim3(8,8,16),256,0,stream>>>(bufQKVb, bufOb);

  // 5. merged tails: {Wo-GEMM+LN+FFN1} -> TO(regs) -> {sw-GEMM+LN+FFN2} -> out
  L2XArgs la;
  la.A=bufOb; la.Wo=Wob; la.xT=x_T; la.ln1w=tl2w; la.ln1b=tl2b;
  la.W1a=f1w1b; la.B1a=f1b1; la.W2a=f1w2b; la.B2a=f1b2;
  la.sw=swB; la.ln2w=flw; la.ln2b=flb;
  la.W1b=f2w1b; la.B1b=f2b1; la.W2b=f2w2b; la.B2b=f2b2;
  la.out0=out0;
  lnffn2x<<<256,512,0,stream>>>(la);
}